// Round 12
// baseline (117.077 us; speedup 1.0000x reference)
//
#include <hip/hip_runtime.h>

// LnnDynamics v13: m gets uniform persistent chunks (tail elimination).
// v12 post-mortem: m stuck at 56us though occupancy rose 22.6->32.5% ->
// occupancy wasn't the limiter. m's 1024 blocks at 3 resident/CU (768
// slots) = one full round + a 256-block TAIL on 1/3 of the machine.
// u (256 blk = 1/CU) and d (512 blk < 768 slots) have no tail and
// behaved as predicted. v13: m grid = (B+127)/128 = 512 blocks (2/CU,
// uniform), each striding over 2 chunks of 64 elements; staging
// amortized 2x. No inter-chunk barrier: an element's 8 lanes are one
// wave; XD/TC ordering is intra-wave program order (v12 invariant).
// u (octet E=2, 1024thr), d (quad E=2), combine, prep unchanged.
// Scratch sc SoA: sc[f*B+b], f: 0-20 Ms, 21-26 tc, 27-32 tp, 33-38 td.

#define NQ 6
#define HID 32
#define NHID 4

// workspace float offsets (built by prep_kernel)
#define MW0T 0
#define UW0T 192
#define DW0T 384
#define MWHT 576
#define UWHT (576 + 4096)
#define DWHT (576 + 8192)
#define MWOT (576 + 12288)
#define DWOT (MWOT + 1152)
#define UWOT (DWOT + 1152)
#define W0P_M 15200
#define W0P_U 15488
#define W0P_D 15744
#define WSYM 16000
#define BSYM 16672
#define SC_BASE 16896

// ---- common LDS slots ----
#define L_W0P 0    // 256 (stride-8 padded W0 rows)
#define L_WHT 256  // 128 rows * 36 -> 4864 (transposed fwd Wh)
// m kernel (octet E=1, 512 thr, 64 el/chunk):
#define LM_WSYM 4864  // 21*36 -> 5620
#define LM_BSYM 5620
#define LM_B0 5644
#define LM_BH 5676  // -> 5804
#define LM_AH 5804  // 64*36 -> 8108
#define LM_AT 8108  // -> 10412
#define LM_XD 10412  // 64*6 -> 10796
#define LM_TC 10796  // -> 11180
#define LM_TOT 11184  // 44.7 KB -> 3 blocks/CU possible; grid sized 2/CU
// u kernel (octet E=2, 1024 thr, 256 el):
#define LU_WHO 4864  // 128*36 -> 9472 (orig-layout Wh for bwd)
#define LU_WO 9472   // 32
#define LU_W0O 9504  // 6*36 -> 9720
#define LU_B0 9720
#define LU_BH 9752  // -> 9880
#define LU_S 9880    // 256*36 -> 19096
#define LU_HB 19096  // -> 28312
#define LU_HD 28312  // -> 37528
#define LU_TOT 37528  // 150.1 KB -> 1 block/CU (16 waves)
// d kernel (quad E=2, 256 thr, 128 el):
#define LD_WOT 4864  // 36*36 -> 6160
#define LD_B0 6160
#define LD_BH 6192
#define LD_BO 6320  // -> 6356
#define LD_S 6356   // 128*36 -> 10964
#define LD_TOT 10964  // 43.9 KB -> 3 blocks/CU

__device__ const int IU21[21] = {0, 0, 0, 0, 0, 0, 1, 1, 1, 1, 1, 2, 2, 2, 2, 3, 3, 3, 4, 4, 5};
__device__ const int JU21[21] = {0, 1, 2, 3, 4, 5, 1, 2, 3, 4, 5, 2, 3, 4, 5, 3, 4, 5, 4, 5, 5};

__global__ void prep_kernel(const float* __restrict__ mW0, const float* __restrict__ mWh,
                            const float* __restrict__ mWo, const float* __restrict__ m_bo,
                            const float* __restrict__ uW0, const float* __restrict__ uWh,
                            const float* __restrict__ uWo, const float* __restrict__ dW0,
                            const float* __restrict__ dWh, const float* __restrict__ dWo,
                            float* __restrict__ ws) {
  int t = blockIdx.x * blockDim.x + threadIdx.x;
  if (t < 192) {
    int j = t / 6, k = t % 6;
    ws[MW0T + t] = mW0[k * HID + j];
    ws[UW0T + t] = uW0[k * HID + j];
    ws[DW0T + t] = dW0[k * HID + j];
  }
  if (t < 256) {  // padded W0p[j*8+k]
    int j = t >> 3, k = t & 7;
    float vm = 0.f, vu = 0.f, vd = 0.f;
    if (k < 6) {
      vm = mW0[k * HID + j];
      vu = uW0[k * HID + j];
      vd = dW0[k * HID + j];
    }
    ws[W0P_M + t] = vm;
    ws[W0P_U + t] = vu;
    ws[W0P_D + t] = vd;
  }
  if (t < 4096) {
    int l = t >> 10, j = (t >> 5) & 31, k = t & 31;
    int src = l * 1024 + k * 32 + j;
    ws[MWHT + t] = mWh[src];
    ws[UWHT + t] = uWh[src];
    ws[DWHT + t] = dWh[src];
  }
  if (t < 1152) {
    int o = t / 32, k = t % 32;
    ws[MWOT + t] = mWo[k * 36 + o];
    ws[DWOT + t] = dWo[k * 36 + o];
  }
  if (t < 32) ws[UWOT + t] = uWo[t];
  if (t < 672) {
    int p = t >> 5, k = t & 31;
    int i = IU21[p], j = JU21[p];
    ws[WSYM + t] = 0.5f * (mWo[k * 36 + i * 6 + j] + mWo[k * 36 + j * 6 + i]);
  }
  if (t < 21) {
    int i = IU21[t], j = JU21[t];
    ws[BSYM + t] = 0.5f * (m_bo[i * 6 + j] + m_bo[j * 6 + i]);
  }
}

__device__ __forceinline__ float sp1(float z) {
  return fmaxf(z, 0.f) + __logf(1.f + __expf(-fabsf(z)));
}
__device__ __forceinline__ void sp_sig(float z, float& hs, float& sg) {
  float e = __expf(-fabsf(z));
  float d = __builtin_amdgcn_rcpf(1.f + e);
  hs = fmaxf(z, 0.f) + __logf(1.f + e);
  sg = (z >= 0.f ? 1.f : e) * d;
}
__device__ __forceinline__ float sig_h(float h) { return 1.f - __expf(-h); }

__device__ __forceinline__ void cpy4n(float* __restrict__ dst, const float* __restrict__ src,
                                      int n4, int t, int nt) {
  const float4* s = (const float4*)src;
  float4* d = (float4*)dst;
  for (int i = t; i < n4; i += nt) d[i] = s[i];
}
__device__ __forceinline__ void cpysn(float* __restrict__ dst, const float* __restrict__ src,
                                      int n, int t, int nt) {
  for (int i = t; i < n; i += nt) dst[i] = src[i];
}
__device__ __forceinline__ void stage36n(float* __restrict__ dst, const float* __restrict__ src,
                                         int nrows, int t, int nt) {
  int n4 = nrows * 8;
  for (int i = t; i < n4; i += nt) {
    int r = i >> 3, c = i & 7;
    *(float4*)&dst[r * 36 + c * 4] = *(const float4*)&src[r * 32 + c * 4];
  }
}

__device__ __forceinline__ void load32(const float* p, float* hv) {
#pragma unroll
  for (int c = 0; c < 8; c++) {
    float4 v = *(const float4*)&p[4 * c];
    hv[4 * c + 0] = v.x;
    hv[4 * c + 1] = v.y;
    hv[4 * c + 2] = v.z;
    hv[4 * c + 3] = v.w;
  }
}
__device__ __forceinline__ float dot32(const float* hv, const float* r) {
  float s = 0.f;
#pragma unroll
  for (int c = 0; c < 8; c++) {
    float4 w = *(const float4*)&r[4 * c];
    s += hv[4 * c + 0] * w.x + hv[4 * c + 1] * w.y + hv[4 * c + 2] * w.z + hv[4 * c + 3] * w.w;
  }
  return s;
}

// ---- quad (4-lane) E=2 fwd layer, 8 rows/lane: d kernel ----
__device__ __forceinline__ void coopFwd2(const float* Wb, const float* bh, const float* s0,
                                         const float* s1, float* d0, float* d1, int q) {
  float a0[32], a1[32];
  load32(s0, a0);
  load32(s1, a1);
#pragma unroll 2
  for (int m8 = 0; m8 < 8; m8++) {
    int j = q + 4 * m8;
    const float* r = Wb + j * 36;
    float z0 = bh[j], z1 = bh[j];
#pragma unroll
    for (int c = 0; c < 8; c++) {
      float4 w = *(const float4*)&r[4 * c];
      z0 += a0[4 * c + 0] * w.x + a0[4 * c + 1] * w.y + a0[4 * c + 2] * w.z + a0[4 * c + 3] * w.w;
      z1 += a1[4 * c + 0] * w.x + a1[4 * c + 1] * w.y + a1[4 * c + 2] * w.z + a1[4 * c + 3] * w.w;
    }
    d0[j] = sp1(z0);
    d1[j] = sp1(z1);
  }
}
// ---- octet (8-lane) E=2 fwd layer, 4 rows/lane: u kernel ----
__device__ __forceinline__ void coopFwd2O(const float* Wb, const float* bh, const float* s0,
                                          const float* s1, float* d0, float* d1, int o) {
  float a0[32], a1[32];
  load32(s0, a0);
  load32(s1, a1);
#pragma unroll
  for (int m4 = 0; m4 < 4; m4++) {
    int j = o + 8 * m4;
    const float* r = Wb + j * 36;
    float z0 = bh[j], z1 = bh[j];
#pragma unroll
    for (int c = 0; c < 8; c++) {
      float4 w = *(const float4*)&r[4 * c];
      z0 += a0[4 * c + 0] * w.x + a0[4 * c + 1] * w.y + a0[4 * c + 2] * w.z + a0[4 * c + 3] * w.w;
      z1 += a1[4 * c + 0] * w.x + a1[4 * c + 1] * w.y + a1[4 * c + 2] * w.z + a1[4 * c + 3] * w.w;
    }
    d0[j] = sp1(z0);
    d1[j] = sp1(z1);
  }
}
// ---- octet E=2 bwd matvec, 4 rows/lane ----
__device__ __forceinline__ void coopBwd2O(const float* Wb, const float* s0, const float* s1,
                                          float* d0, float* d1, int o) {
  float a0[32], a1[32];
  load32(s0, a0);
  load32(s1, a1);
#pragma unroll
  for (int m4 = 0; m4 < 4; m4++) {
    int k = o + 8 * m4;
    const float* r = Wb + k * 36;
    float z0 = 0.f, z1 = 0.f;
#pragma unroll
    for (int c = 0; c < 8; c++) {
      float4 w = *(const float4*)&r[4 * c];
      z0 += a0[4 * c + 0] * w.x + a0[4 * c + 1] * w.y + a0[4 * c + 2] * w.z + a0[4 * c + 3] * w.w;
      z1 += a1[4 * c + 0] * w.x + a1[4 * c + 1] * w.y + a1[4 * c + 2] * w.z + a1[4 * c + 3] * w.w;
    }
    d0[k] = z0;
    d1[k] = z1;
  }
}
// ---- octet E=1 fused value+tangent layer, 4 rows/lane: m kernel ----
__device__ __forceinline__ void coopFusedO(const float* Wb, const float* bh, float* ah, float* at,
                                           int o) {
  float hv[32], tv[32];
  load32(ah, hv);
  load32(at, tv);
#pragma unroll
  for (int m4 = 0; m4 < 4; m4++) {
    int j = o + 8 * m4;
    const float* r = Wb + j * 36;
    float zh = bh[j], zt = 0.f;
#pragma unroll
    for (int c = 0; c < 8; c++) {
      float4 w = *(const float4*)&r[4 * c];
      zh += hv[4 * c + 0] * w.x + hv[4 * c + 1] * w.y + hv[4 * c + 2] * w.z + hv[4 * c + 3] * w.w;
      zt += tv[4 * c + 0] * w.x + tv[4 * c + 1] * w.y + tv[4 * c + 2] * w.z + tv[4 * c + 3] * w.w;
    }
    float hs, sg;
    sp_sig(zh, hs, sg);
    ah[j] = hs;
    at[j] = zt * sg;
  }
}

// ================= m kernel (octet E=1, 512 thr, chunked) =================
__global__ __launch_bounds__(512, 1) void mrole_kernel(const float* __restrict__ in,
                                                       const float* __restrict__ ws,
                                                       const float* __restrict__ m_b0,
                                                       const float* __restrict__ m_bh,
                                                       float* __restrict__ sc, int B) {
  __shared__ __align__(16) float L[LM_TOT];
  __shared__ int PIJ[21];
  const int t = threadIdx.x;
  cpy4n(L + L_W0P, ws + W0P_M, 64, t, 512);
  stage36n(L + L_WHT, ws + MWHT, 128, t, 512);
  stage36n(L + LM_WSYM, ws + WSYM, 21, t, 512);
  cpysn(L + LM_BSYM, ws + BSYM, 21, t, 512);
  cpysn(L + LM_B0, m_b0, 32, t, 512);
  cpysn(L + LM_BH, m_bh, 128, t, 512);
  if (t < 21) PIJ[t] = (IU21[t] << 3) | JU21[t];
  __syncthreads();

  const int el = t >> 3, o = t & 7;
  const long Bl = B;
  const int eoff = el * 36;
  const int estep = gridDim.x * 64;

  // uniform persistent chunks: no dispatch tail. Each element's 8 lanes
  // are one wave; XD/TC zero->write->atomic ordering is program order.
  for (int base = blockIdx.x * 64; base < B; base += estep) {
    const int e = base + el;
    if (e >= B) continue;
    const float* ip = in + (long)e * 18;

    float x0 = ip[0], x1 = ip[1], x2 = ip[2], x3 = ip[3], x4 = ip[4], x5 = ip[5];
    float d0 = ip[6], d1 = ip[7], d2 = ip[8], d3 = ip[9], d4 = ip[10], d5 = ip[11];
    if (o < 6) {
      L[LM_XD + el * 6 + o] = ip[6 + o];
      L[LM_TC + el * 6 + o] = 0.f;
    }
    float* aH = L + LM_AH + eoff;
    float* aT = L + LM_AT + eoff;
#pragma unroll
    for (int m4 = 0; m4 < 4; m4++) {
      int j = o + 8 * m4;
      float4 wa = *(const float4*)&L[L_W0P + j * 8];
      float4 wb = *(const float4*)&L[L_W0P + j * 8 + 4];
      float zh = L[LM_B0 + j] + x0 * wa.x + x1 * wa.y + x2 * wa.z + x3 * wa.w + x4 * wb.x +
                 x5 * wb.y;
      float zt = d0 * wa.x + d1 * wa.y + d2 * wa.z + d3 * wa.w + d4 * wb.x + d5 * wb.y;
      float hs, sg;
      sp_sig(zh, hs, sg);
      aH[j] = hs;
      aT[j] = zt * sg;
    }
#pragma unroll 1
    for (int l = 0; l < 4; l++) coopFusedO(L + L_WHT + l * 1152, L + LM_BH + l * 32, aH, aT, o);
    float hv[32], tv[32];
    load32(aH, hv);
    load32(aT, tv);
#pragma unroll 1
    for (int mm = 0; mm < 3; mm++) {
      int p = o + 8 * mm;
      if (p < 21) {
        const float* r = L + LM_WSYM + p * 36;
        float v = L[LM_BSYM + p] + dot32(hv, r);
        float w = dot32(tv, r);
        sc[(long)p * Bl + e] = v;
        int pij = PIJ[p];
        int iu = pij >> 3, ju = pij & 7;
        float xdj = L[LM_XD + el * 6 + ju];
        atomicAdd(&L[LM_TC + el * 6 + iu], w * xdj);
        if (iu != ju) {
          float xdi = L[LM_XD + el * 6 + iu];
          atomicAdd(&L[LM_TC + el * 6 + ju], w * xdi);
        }
      }
    }
    if (o < 6) sc[(long)(21 + o) * Bl + e] = L[LM_TC + el * 6 + o];
  }
}

// ================= u kernel (octet E=2, 1024 thr, 256 el) =================
__global__ __launch_bounds__(1024, 1) void urole_kernel(
    const float* __restrict__ in, const float* __restrict__ ws, const float* __restrict__ u_W0,
    const float* __restrict__ u_b0, const float* __restrict__ u_Wh, const float* __restrict__ u_bh,
    const float* __restrict__ u_Wo, float* __restrict__ sc, int B) {
  __shared__ __align__(16) float L[LU_TOT];
  const int t = threadIdx.x;
  cpy4n(L + L_W0P, ws + W0P_U, 64, t, 1024);
  stage36n(L + L_WHT, ws + UWHT, 128, t, 1024);
  stage36n(L + LU_WHO, u_Wh, 128, t, 1024);
  cpy4n(L + LU_WO, u_Wo, 8, t, 1024);
  stage36n(L + LU_W0O, u_W0, 6, t, 1024);
  cpysn(L + LU_B0, u_b0, 32, t, 1024);
  cpysn(L + LU_BH, u_bh, 128, t, 1024);
  __syncthreads();

  const int oid = t >> 3, o = t & 7;
  const int e0 = blockIdx.x * 256 + oid;
  if (e0 >= B) return;
  const int e1 = e0 + 128;
  const bool has1 = e1 < B;
  const int el0 = oid, el1 = oid + 128;
  const float* ip0 = in + (long)e0 * 18;
  const float* ip1 = in + (long)(has1 ? e1 : e0) * 18;
  const long Bl = B;

  float X0[6], X1[6];
#pragma unroll
  for (int i = 0; i < 6; i++) {
    X0[i] = ip0[i];
    X1[i] = ip1[i];
  }
  float* S0 = L + LU_S + el0 * 36;
  float* S1 = L + LU_S + el1 * 36;
  float* HB0 = L + LU_HB + el0 * 36;
  float* HB1 = L + LU_HB + el1 * 36;
  float* HD0 = L + LU_HD + el0 * 36;
  float* HD1 = L + LU_HD + el1 * 36;
#pragma unroll
  for (int m4 = 0; m4 < 4; m4++) {
    int j = o + 8 * m4;
    float4 wa = *(const float4*)&L[L_W0P + j * 8];
    float4 wb = *(const float4*)&L[L_W0P + j * 8 + 4];
    float b = L[LU_B0 + j];
    S0[j] = sp1(b + X0[0] * wa.x + X0[1] * wa.y + X0[2] * wa.z + X0[3] * wa.w + X0[4] * wb.x +
                X0[5] * wb.y);
    S1[j] = sp1(b + X1[0] * wa.x + X1[1] * wa.y + X1[2] * wa.z + X1[3] * wa.w + X1[4] * wb.x +
                X1[5] * wb.y);
  }
  coopFwd2O(L + L_WHT + 0 * 1152, L + LU_BH + 0, S0, S1, HB0, HB1, o);
  coopFwd2O(L + L_WHT + 1 * 1152, L + LU_BH + 32, HB0, HB1, S0, S1, o);
  coopFwd2O(L + L_WHT + 2 * 1152, L + LU_BH + 64, S0, S1, HD0, HD1, o);
  coopFwd2O(L + L_WHT + 3 * 1152, L + LU_BH + 96, HD0, HD1, S0, S1, o);
#pragma unroll
  for (int m4 = 0; m4 < 4; m4++) {
    int j = o + 8 * m4;
    float wo = L[LU_WO + j];
    S0[j] = wo * sig_h(S0[j]);
    S1[j] = wo * sig_h(S1[j]);
  }
  coopBwd2O(L + LU_WHO + 3 * 1152, S0, S1, S0, S1, o);
#pragma unroll
  for (int m4 = 0; m4 < 4; m4++) {
    int j = o + 8 * m4;
    S0[j] = S0[j] * sig_h(HD0[j]);
    S1[j] = S1[j] * sig_h(HD1[j]);
  }
  coopBwd2O(L + LU_WHO + 2 * 1152, S0, S1, HD0, HD1, o);
  coopFwd2O(L + L_WHT + 1 * 1152, L + LU_BH + 32, HB0, HB1, S0, S1, o);  // recompute hc
#pragma unroll
  for (int m4 = 0; m4 < 4; m4++) {
    int j = o + 8 * m4;
    HD0[j] = HD0[j] * sig_h(S0[j]);
    HD1[j] = HD1[j] * sig_h(S1[j]);
  }
  coopBwd2O(L + LU_WHO + 1 * 1152, HD0, HD1, S0, S1, o);
#pragma unroll
  for (int m4 = 0; m4 < 4; m4++) {
    int j = o + 8 * m4;
    HB0[j] = S0[j] * sig_h(HB0[j]);
    HB1[j] = S1[j] * sig_h(HB1[j]);
  }
  coopBwd2O(L + LU_WHO + 0 * 1152, HB0, HB1, HD0, HD1, o);
#pragma unroll
  for (int m4 = 0; m4 < 4; m4++) {
    int j = o + 8 * m4;
    float4 wa = *(const float4*)&L[L_W0P + j * 8];
    float4 wb = *(const float4*)&L[L_W0P + j * 8 + 4];
    float b = L[LU_B0 + j];
    float a0 = sp1(b + X0[0] * wa.x + X0[1] * wa.y + X0[2] * wa.z + X0[3] * wa.w + X0[4] * wb.x +
                   X0[5] * wb.y);
    float a1 = sp1(b + X1[0] * wa.x + X1[1] * wa.y + X1[2] * wa.z + X1[3] * wa.w + X1[4] * wb.x +
                   X1[5] * wb.y);
    S0[j] = HD0[j] * sig_h(a0);
    S1[j] = HD1[j] * sig_h(a1);
  }
  if (o < 6) {
    float a0[32], a1[32];
    load32(S0, a0);
    load32(S1, a1);
    const float* r = L + LU_W0O + o * 36;
    float tp0 = 0.f, tp1 = 0.f;
#pragma unroll
    for (int c = 0; c < 8; c++) {
      float4 w = *(const float4*)&r[4 * c];
      tp0 += a0[4 * c + 0] * w.x + a0[4 * c + 1] * w.y + a0[4 * c + 2] * w.z + a0[4 * c + 3] * w.w;
      tp1 += a1[4 * c + 0] * w.x + a1[4 * c + 1] * w.y + a1[4 * c + 2] * w.z + a1[4 * c + 3] * w.w;
    }
    sc[(long)(27 + o) * Bl + e0] = tp0;
    if (has1) sc[(long)(27 + o) * Bl + e1] = tp1;
  }
}

// ================= d kernel (quad E=2, 256 thr, 128 el) =================
__global__ __launch_bounds__(256, 1) void drole_kernel(const float* __restrict__ in,
                                                       const float* __restrict__ ws,
                                                       const float* __restrict__ d_b0,
                                                       const float* __restrict__ d_bh,
                                                       const float* __restrict__ d_bo,
                                                       float* __restrict__ sc, int B) {
  __shared__ __align__(16) float L[LD_TOT];
  const int t = threadIdx.x;
  cpy4n(L + L_W0P, ws + W0P_D, 64, t, 256);
  stage36n(L + L_WHT, ws + DWHT, 128, t, 256);
  stage36n(L + LD_WOT, ws + DWOT, 36, t, 256);
  cpysn(L + LD_B0, d_b0, 32, t, 256);
  cpysn(L + LD_BH, d_bh, 128, t, 256);
  cpysn(L + LD_BO, d_bo, 36, t, 256);
  __syncthreads();

  const int qid = t >> 2, q = t & 3;
  const int e0 = blockIdx.x * 128 + qid;
  if (e0 >= B) return;
  const int e1 = e0 + 64;
  const bool has1 = e1 < B;
  const int el0 = qid, el1 = qid + 64;
  const float* ip0 = in + (long)e0 * 18;
  const float* ip1 = in + (long)(has1 ? e1 : e0) * 18;
  const long Bl = B;

  float X0[6], X1[6];
#pragma unroll
  for (int i = 0; i < 6; i++) {
    X0[i] = ip0[i];
    X1[i] = ip1[i];
  }
  float* S0 = L + LD_S + el0 * 36;
  float* S1 = L + LD_S + el1 * 36;
#pragma unroll 2
  for (int m8 = 0; m8 < 8; m8++) {
    int j = q + 4 * m8;
    float4 wa = *(const float4*)&L[L_W0P + j * 8];
    float4 wb = *(const float4*)&L[L_W0P + j * 8 + 4];
    float b = L[LD_B0 + j];
    S0[j] = sp1(b + X0[0] * wa.x + X0[1] * wa.y + X0[2] * wa.z + X0[3] * wa.w + X0[4] * wb.x +
                X0[5] * wb.y);
    S1[j] = sp1(b + X1[0] * wa.x + X1[1] * wa.y + X1[2] * wa.z + X1[3] * wa.w + X1[4] * wb.x +
                X1[5] * wb.y);
  }
#pragma unroll 1
  for (int l = 0; l < 4; l++)
    coopFwd2(L + L_WHT + l * 1152, L + LD_BH + l * 32, S0, S1, S0, S1, q);
  float a0[32], a1[32];
  load32(S0, a0);
  load32(S1, a1);
#pragma unroll 1
  for (int mm = 0; mm < 2; mm++) {
    int i = q + 4 * mm;
    if (i < 6) {
      float td0 = 0.f, td1 = 0.f;
#pragma unroll 1
      for (int c = 0; c < 6; c++) {
        const float* r = L + LD_WOT + (i * 6 + c) * 36;
        float b = L[LD_BO + i * 6 + c];
        float v0 = b, v1 = b;
#pragma unroll
        for (int cc = 0; cc < 8; cc++) {
          float4 w = *(const float4*)&r[4 * cc];
          v0 += a0[4 * cc + 0] * w.x + a0[4 * cc + 1] * w.y + a0[4 * cc + 2] * w.z +
                a0[4 * cc + 3] * w.w;
          v1 += a1[4 * cc + 0] * w.x + a1[4 * cc + 1] * w.y + a1[4 * cc + 2] * w.z +
                a1[4 * cc + 3] * w.w;
        }
        td0 += v0 * ip0[6 + c];
        td1 += v1 * ip1[6 + c];
      }
      sc[(long)(33 + i) * Bl + e0] = td0;
      if (has1) sc[(long)(33 + i) * Bl + e1] = td1;
    }
  }
}

// ---------------- combine + solve (unchanged) ----------------
__global__ __launch_bounds__(256) void combine_kernel(const float* __restrict__ in,
                                                      const float* __restrict__ A,
                                                      const float* __restrict__ sc,
                                                      float* __restrict__ out, int B) {
  int b = blockIdx.x * 256 + threadIdx.x;
  if (b >= B) return;
  const long Bl = B;
  const float* ip = in + (long)b * 18;
  float te[6];
  {
    float tv[6];
#pragma unroll
    for (int i = 0; i < 6; i++) tv[i] = ip[12 + i];
#pragma unroll
    for (int i = 0; i < 6; i++) {
      float s = 0.f;
#pragma unroll
      for (int j = 0; j < 6; j++) s += tv[j] * A[j * 6 + i];
      te[i] = s;
    }
  }
  float Ms[6][6], r[6], y[6];
  {
    int idx = 0;
#pragma unroll
    for (int i = 0; i < 6; i++)
#pragma unroll
      for (int j = i; j < 6; j++) {
        float v = sc[idx * Bl + b];
        Ms[i][j] = v;
        Ms[j][i] = v;
        idx++;
      }
  }
#pragma unroll
  for (int i = 0; i < 6; i++)
    r[i] = te[i] - sc[(21 + i) * Bl + b] - sc[(27 + i) * Bl + b] - sc[(33 + i) * Bl + b];

#pragma unroll
  for (int k = 0; k < 6; k++) {
#pragma unroll
    for (int rr = k + 1; rr < 6; rr++) {
      bool c = fabsf(Ms[rr][k]) > fabsf(Ms[k][k]);
#pragma unroll
      for (int j = 0; j < 6; j++) {
        float a = Ms[k][j], bb = Ms[rr][j];
        Ms[k][j] = c ? bb : a;
        Ms[rr][j] = c ? a : bb;
      }
      float a = r[k], bb = r[rr];
      r[k] = c ? bb : a;
      r[rr] = c ? a : bb;
    }
    float piv = Ms[k][k];
#pragma unroll
    for (int rr = k + 1; rr < 6; rr++) {
      float f = Ms[rr][k] / piv;
#pragma unroll
      for (int j = k; j < 6; j++) Ms[rr][j] -= f * Ms[k][j];
      r[rr] -= f * r[k];
    }
  }
#pragma unroll
  for (int ki = 5; ki >= 0; ki--) {
    float v = r[ki];
#pragma unroll
    for (int j = ki + 1; j < 6; j++) v -= Ms[ki][j] * y[j];
    y[ki] = v / Ms[ki][ki];
  }
  float* op = out + (long)b * 6;
#pragma unroll
  for (int i = 0; i < 6; i++) op[i] = y[i];
}

// ---------------- fallback monolithic kernel ----------------
__device__ __forceinline__ void fwd_layer(const float* __restrict__ Wb,
                                          const float* __restrict__ bh,
                                          const float* __restrict__ hin, float* __restrict__ hout) {
#pragma unroll
  for (int j = 0; j < 32; j++) {
    const float* r = Wb + j * 32;
    float z = bh[j];
#pragma unroll
    for (int k = 0; k < 32; k++) z += hin[k] * r[k];
    hout[j] = sp1(z);
  }
}
__device__ __forceinline__ void m_layer(const float* __restrict__ Wb, const float* __restrict__ bh,
                                        float* __restrict__ h, const float* __restrict__ tin,
                                        float* __restrict__ tout) {
#pragma unroll
  for (int j = 0; j < 32; j++) {
    const float* r = Wb + j * 32;
    float z = bh[j];
#pragma unroll
    for (int k = 0; k < 32; k++) z += h[k] * r[k];
    tout[j] = z;
  }
#pragma unroll
  for (int j = 0; j < 32; j++) {
    const float* r = Wb + j * 32;
    float z = 0.f;
#pragma unroll
    for (int k = 0; k < 32; k++) z += tin[k] * r[k];
    float hs, sg;
    sp_sig(tout[j], hs, sg);
    h[j] = hs;
    tout[j] = z * sg;
  }
}
__device__ __forceinline__ void bwd_mv(const float* __restrict__ Worig,
                                       const float* __restrict__ gin, float* __restrict__ gout) {
#pragma unroll
  for (int k = 0; k < 32; k++) {
    const float* r = Worig + k * 32;
    float s = 0.f;
#pragma unroll
    for (int j = 0; j < 32; j++) s += r[j] * gin[j];
    gout[k] = s;
  }
}

__global__ __launch_bounds__(64, 1) void lnn_kernel(
    const float* __restrict__ in, const float* __restrict__ A, const float* __restrict__ ws,
    const float* __restrict__ m_b0, const float* __restrict__ m_bh, const float* __restrict__ m_bo,
    const float* __restrict__ u_W0, const float* __restrict__ u_b0, const float* __restrict__ u_Wh,
    const float* __restrict__ u_bh, const float* __restrict__ u_Wo,
    const float* __restrict__ d_b0, const float* __restrict__ d_bh, const float* __restrict__ d_bo,
    float* __restrict__ out, int B) {
  int b = blockIdx.x * 64 + threadIdx.x;
  if (b >= B) return;
  const float* ip = in + (long)b * 18;
  float x[6], xd[6], te[6];
#pragma unroll
  for (int i = 0; i < 6; i++) {
    x[i] = ip[i];
    xd[i] = ip[6 + i];
  }
  {
    float tv[6];
#pragma unroll
    for (int i = 0; i < 6; i++) tv[i] = ip[12 + i];
#pragma unroll
    for (int i = 0; i < 6; i++) {
      float s = 0.f;
#pragma unroll
      for (int j = 0; j < 6; j++) s += tv[j] * A[j * 6 + i];
      te[i] = s;
    }
  }
  float td[6] = {0, 0, 0, 0, 0, 0};
  {
    float h[32], zn[32];
    const float* w0 = ws + DW0T;
#pragma unroll
    for (int j = 0; j < 32; j++) {
      float z = d_b0[j];
#pragma unroll
      for (int k = 0; k < 6; k++) z += x[k] * w0[j * 6 + k];
      h[j] = sp1(z);
    }
    fwd_layer(ws + DWHT + 0 * 1024, d_bh + 0, h, zn);
    fwd_layer(ws + DWHT + 1 * 1024, d_bh + 32, zn, h);
    fwd_layer(ws + DWHT + 2 * 1024, d_bh + 64, h, zn);
    fwd_layer(ws + DWHT + 3 * 1024, d_bh + 96, zn, h);
    const float* wo = ws + DWOT;
#pragma unroll
    for (int o = 0; o < 36; o++) {
      float v = d_bo[o];
#pragma unroll
      for (int k = 0; k < 32; k++) v += h[k] * wo[o * 32 + k];
      td[o / 6] += v * xd[o % 6];
    }
  }
  float tp[6] = {0, 0, 0, 0, 0, 0};
  {
    float hb[32], hd[32], s[32], r2[32];
    const float* w0 = ws + UW0T;
#pragma unroll
    for (int j = 0; j < 32; j++) {
      float z = u_b0[j];
#pragma unroll
      for (int k = 0; k < 6; k++) z += x[k] * w0[j * 6 + k];
      s[j] = sp1(z);
    }
    fwd_layer(ws + UWHT + 0 * 1024, u_bh + 0, s, hb);
    fwd_layer(ws + UWHT + 1 * 1024, u_bh + 32, hb, s);
    fwd_layer(ws + UWHT + 2 * 1024, u_bh + 64, s, hd);
    fwd_layer(ws + UWHT + 3 * 1024, u_bh + 96, hd, s);
#pragma unroll
    for (int j = 0; j < 32; j++) s[j] = u_Wo[j] * sig_h(s[j]);
    bwd_mv(u_Wh + 3 * 1024, s, r2);
#pragma unroll
    for (int j = 0; j < 32; j++) s[j] = r2[j] * sig_h(hd[j]);
    bwd_mv(u_Wh + 2 * 1024, s, hd);
    fwd_layer(ws + UWHT + 1 * 1024, u_bh + 32, hb, s);
#pragma unroll
    for (int j = 0; j < 32; j++) r2[j] = hd[j] * sig_h(s[j]);
    bwd_mv(u_Wh + 1 * 1024, r2, s);
#pragma unroll
    for (int j = 0; j < 32; j++) r2[j] = s[j] * sig_h(hb[j]);
    bwd_mv(u_Wh + 0 * 1024, r2, hb);
#pragma unroll
    for (int j = 0; j < 32; j++) {
      float z = u_b0[j];
#pragma unroll
      for (int k = 0; k < 6; k++) z += x[k] * w0[j * 6 + k];
      s[j] = sp1(z);
    }
#pragma unroll
    for (int j = 0; j < 32; j++) s[j] = hb[j] * sig_h(s[j]);
#pragma unroll
    for (int i = 0; i < 6; i++) {
      float t = 0.f;
#pragma unroll
      for (int j = 0; j < 32; j++) t += u_W0[i * 32 + j] * s[j];
      tp[i] = t;
    }
  }
  float Ms[6][6], tc[6];
  {
    float h[32], t[32], zn[32];
    const float* w0 = ws + MW0T;
#pragma unroll
    for (int j = 0; j < 32; j++) {
      float zh = m_b0[j], zt = 0.f;
#pragma unroll
      for (int k = 0; k < 6; k++) {
        zh += x[k] * w0[j * 6 + k];
        zt += xd[k] * w0[j * 6 + k];
      }
      float hs, sg;
      sp_sig(zh, hs, sg);
      h[j] = hs;
      t[j] = zt * sg;
    }
    m_layer(ws + MWHT + 0 * 1024, m_bh + 0, h, t, zn);
    m_layer(ws + MWHT + 1 * 1024, m_bh + 32, h, zn, t);
    m_layer(ws + MWHT + 2 * 1024, m_bh + 64, h, t, zn);
    m_layer(ws + MWHT + 3 * 1024, m_bh + 96, h, zn, t);
    const float* wo = ws + MWOT;
    float Msv[21];
    int idx = 0;
#pragma unroll
    for (int i = 0; i < 6; i++) tc[i] = 0.f;
#pragma unroll
    for (int i = 0; i < 6; i++)
#pragma unroll
      for (int j = i; j < 6; j++) {
        const float* r = wo + (i * 6 + j) * 32;
        float v = m_bo[i * 6 + j], w = 0.f;
#pragma unroll
        for (int k = 0; k < 32; k++) {
          v += h[k] * r[k];
          w += t[k] * r[k];
        }
        if (i != j) {
          const float* rr = wo + (j * 6 + i) * 32;
          float v2 = m_bo[j * 6 + i], w2 = 0.f;
#pragma unroll
          for (int k = 0; k < 32; k++) {
            v2 += h[k] * rr[k];
            w2 += t[k] * rr[k];
          }
          v = 0.5f * (v + v2);
          w = 0.5f * (w + w2);
        }
        Msv[idx] = v;
        tc[i] += w * xd[j];
        if (j != i) tc[j] += w * xd[i];
        idx++;
      }
    idx = 0;
#pragma unroll
    for (int i = 0; i < 6; i++)
#pragma unroll
      for (int j = i; j < 6; j++) {
        Ms[i][j] = Msv[idx];
        Ms[j][i] = Msv[idx];
        idx++;
      }
  }
  float r[6], y[6];
#pragma unroll
  for (int i = 0; i < 6; i++) r[i] = te[i] - tc[i] - tp[i] - td[i];
#pragma unroll
  for (int k = 0; k < 6; k++) {
#pragma unroll
    for (int rr = k + 1; rr < 6; rr++) {
      bool c = fabsf(Ms[rr][k]) > fabsf(Ms[k][k]);
#pragma unroll
      for (int j = 0; j < 6; j++) {
        float a = Ms[k][j], bb = Ms[rr][j];
        Ms[k][j] = c ? bb : a;
        Ms[rr][j] = c ? a : bb;
      }
      float a = r[k], bb = r[rr];
      r[k] = c ? bb : a;
      r[rr] = c ? a : bb;
    }
    float piv = Ms[k][k];
#pragma unroll
    for (int rr = k + 1; rr < 6; rr++) {
      float f = Ms[rr][k] / piv;
#pragma unroll
      for (int j = k; j < 6; j++) Ms[rr][j] -= f * Ms[k][j];
      r[rr] -= f * r[k];
    }
  }
#pragma unroll
  for (int ki = 5; ki >= 0; ki--) {
    float v = r[ki];
#pragma unroll
    for (int j = ki + 1; j < 6; j++) v -= Ms[ki][j] * y[j];
    y[ki] = v / Ms[ki][ki];
  }
  float* op = out + (long)b * 6;
#pragma unroll
  for (int i = 0; i < 6; i++) op[i] = y[i];
}

extern "C" void kernel_launch(void* const* d_in, const int* in_sizes, int n_in, void* d_out,
                              int out_size, void* d_ws, size_t ws_size, hipStream_t stream) {
  const float* inputs = (const float*)d_in[0];
  const float* A = (const float*)d_in[1];
  const float* m_W0 = (const float*)d_in[2];
  const float* m_b0 = (const float*)d_in[3];
  const float* m_Wh = (const float*)d_in[4];
  const float* m_bh = (const float*)d_in[5];
  const float* m_Wo = (const float*)d_in[6];
  const float* m_bo = (const float*)d_in[7];
  const float* u_W0 = (const float*)d_in[8];
  const float* u_b0 = (const float*)d_in[9];
  const float* u_Wh = (const float*)d_in[10];
  const float* u_bh = (const float*)d_in[11];
  const float* u_Wo = (const float*)d_in[12];
  const float* d_W0 = (const float*)d_in[14];
  const float* d_b0 = (const float*)d_in[15];
  const float* d_Wh = (const float*)d_in[16];
  const float* d_bh = (const float*)d_in[17];
  const float* d_Wo = (const float*)d_in[18];
  const float* d_bo = (const float*)d_in[19];

  float* ws = (float*)d_ws;
  float* out = (float*)d_out;
  int B = in_sizes[0] / 18;

  prep_kernel<<<16, 256, 0, stream>>>(m_W0, m_Wh, m_Wo, m_bo, u_W0, u_Wh, u_Wo, d_W0, d_Wh, d_Wo,
                                      ws);

  size_t need = (size_t)(SC_BASE + (size_t)B * 39) * 4;
  if (ws_size >= need) {
    float* sc = ws + SC_BASE;
    int nb_m = (B + 127) / 128;  // 2 chunks of 64 per block -> 2 blocks/CU uniform
    int nb_d = (B + 127) / 128;
    int nb_u = (B + 255) / 256;
    mrole_kernel<<<nb_m, 512, 0, stream>>>(inputs, ws, m_b0, m_bh, sc, B);
    urole_kernel<<<nb_u, 1024, 0, stream>>>(inputs, ws, u_W0, u_b0, u_Wh, u_bh, u_Wo, sc, B);
    drole_kernel<<<nb_d, 256, 0, stream>>>(inputs, ws, d_b0, d_bh, d_bo, sc, B);
    combine_kernel<<<(B + 255) / 256, 256, 0, stream>>>(inputs, A, sc, out, B);
  } else {
    lnn_kernel<<<(B + 63) / 64, 64, 0, stream>>>(inputs, A, ws, m_b0, m_bh, m_bo, u_W0, u_b0, u_Wh,
                                                 u_bh, u_Wo, d_b0, d_bh, d_bo, out, B);
  }
}

// Round 13
// 109.284 us; speedup vs baseline: 1.0713x; 1.0713x over previous
//
#include <hip/hip_runtime.h>

// LnnDynamics v14: m uses interleaved h/t activations + float2 (packed
// FMA) accumulation; m grid reverted to v12 (1024 blk, 3/CU + tail --
// v13's uniform-2/CU was worse, tail theory falsified).
// Evidence: m time invariant (56-59us) across occupancy 19/22.6/32.5%
// -> throughput-bound. VALUBusy 56% = ~32us issue vs ~8us FMA floor:
// each weight feeds TWO scalar FMAs (zh,zt). CDNA4 has v_pk_fma_f32;
// storing (h,t) interleaved and accumulating float2 pairs exposes it,
// potentially halving m's inner-loop VALU instrs; also halves ds_writes
// and applies to the (v,w) output stage. Stride-76 rows: el*76 mod 32 =
// el*12 -> 8 distinct banks across the octet.
// u (octet E=2, 1024thr), d (quad E=2), combine, prep unchanged.
// Scratch sc SoA: sc[f*B+b], f: 0-20 Ms, 21-26 tc, 27-32 tp, 33-38 td.

#define NQ 6
#define HID 32
#define NHID 4

// workspace float offsets (built by prep_kernel)
#define MW0T 0
#define UW0T 192
#define DW0T 384
#define MWHT 576
#define UWHT (576 + 4096)
#define DWHT (576 + 8192)
#define MWOT (576 + 12288)
#define DWOT (MWOT + 1152)
#define UWOT (DWOT + 1152)
#define W0P_M 15200
#define W0P_U 15488
#define W0P_D 15744
#define WSYM 16000
#define BSYM 16672
#define SC_BASE 16896

// ---- common LDS slots ----
#define L_W0P 0    // 256 (stride-8 padded W0 rows)
#define L_WHT 256  // 128 rows * 36 -> 4864 (transposed fwd Wh)
// m kernel (octet E=1, 512 thr, 64 el, interleaved ht):
#define LM_WSYM 4864  // 21*36 -> 5620
#define LM_BSYM 5620
#define LM_B0 5644
#define LM_BH 5676  // -> 5804
#define LM_HT 5804  // 64 el * 76 (interleaved h,t; 19 float4 rows) -> 10668
#define LM_XD 10668  // 64*6 -> 11052
#define LM_TC 11052  // -> 11436
#define LM_TOT 11440  // 45.8 KB -> 3 blocks/CU
// u kernel (octet E=2, 1024 thr, 256 el):
#define LU_WHO 4864  // 128*36 -> 9472 (orig-layout Wh for bwd)
#define LU_WO 9472   // 32
#define LU_W0O 9504  // 6*36 -> 9720
#define LU_B0 9720
#define LU_BH 9752  // -> 9880
#define LU_S 9880    // 256*36 -> 19096
#define LU_HB 19096  // -> 28312
#define LU_HD 28312  // -> 37528
#define LU_TOT 37528  // 150.1 KB -> 1 block/CU (16 waves)
// d kernel (quad E=2, 256 thr, 128 el):
#define LD_WOT 4864  // 36*36 -> 6160
#define LD_B0 6160
#define LD_BH 6192
#define LD_BO 6320  // -> 6356
#define LD_S 6356   // 128*36 -> 10964
#define LD_TOT 10964  // 43.9 KB -> 3 blocks/CU

__device__ const int IU21[21] = {0, 0, 0, 0, 0, 0, 1, 1, 1, 1, 1, 2, 2, 2, 2, 3, 3, 3, 4, 4, 5};
__device__ const int JU21[21] = {0, 1, 2, 3, 4, 5, 1, 2, 3, 4, 5, 2, 3, 4, 5, 3, 4, 5, 4, 5, 5};

__global__ void prep_kernel(const float* __restrict__ mW0, const float* __restrict__ mWh,
                            const float* __restrict__ mWo, const float* __restrict__ m_bo,
                            const float* __restrict__ uW0, const float* __restrict__ uWh,
                            const float* __restrict__ uWo, const float* __restrict__ dW0,
                            const float* __restrict__ dWh, const float* __restrict__ dWo,
                            float* __restrict__ ws) {
  int t = blockIdx.x * blockDim.x + threadIdx.x;
  if (t < 192) {
    int j = t / 6, k = t % 6;
    ws[MW0T + t] = mW0[k * HID + j];
    ws[UW0T + t] = uW0[k * HID + j];
    ws[DW0T + t] = dW0[k * HID + j];
  }
  if (t < 256) {  // padded W0p[j*8+k]
    int j = t >> 3, k = t & 7;
    float vm = 0.f, vu = 0.f, vd = 0.f;
    if (k < 6) {
      vm = mW0[k * HID + j];
      vu = uW0[k * HID + j];
      vd = dW0[k * HID + j];
    }
    ws[W0P_M + t] = vm;
    ws[W0P_U + t] = vu;
    ws[W0P_D + t] = vd;
  }
  if (t < 4096) {
    int l = t >> 10, j = (t >> 5) & 31, k = t & 31;
    int src = l * 1024 + k * 32 + j;
    ws[MWHT + t] = mWh[src];
    ws[UWHT + t] = uWh[src];
    ws[DWHT + t] = dWh[src];
  }
  if (t < 1152) {
    int o = t / 32, k = t % 32;
    ws[MWOT + t] = mWo[k * 36 + o];
    ws[DWOT + t] = dWo[k * 36 + o];
  }
  if (t < 32) ws[UWOT + t] = uWo[t];
  if (t < 672) {
    int p = t >> 5, k = t & 31;
    int i = IU21[p], j = JU21[p];
    ws[WSYM + t] = 0.5f * (mWo[k * 36 + i * 6 + j] + mWo[k * 36 + j * 6 + i]);
  }
  if (t < 21) {
    int i = IU21[t], j = JU21[t];
    ws[BSYM + t] = 0.5f * (m_bo[i * 6 + j] + m_bo[j * 6 + i]);
  }
}

__device__ __forceinline__ float sp1(float z) {
  return fmaxf(z, 0.f) + __logf(1.f + __expf(-fabsf(z)));
}
__device__ __forceinline__ void sp_sig(float z, float& hs, float& sg) {
  float e = __expf(-fabsf(z));
  float d = __builtin_amdgcn_rcpf(1.f + e);
  hs = fmaxf(z, 0.f) + __logf(1.f + e);
  sg = (z >= 0.f ? 1.f : e) * d;
}
__device__ __forceinline__ float sig_h(float h) { return 1.f - __expf(-h); }

__device__ __forceinline__ void cpy4n(float* __restrict__ dst, const float* __restrict__ src,
                                      int n4, int t, int nt) {
  const float4* s = (const float4*)src;
  float4* d = (float4*)dst;
  for (int i = t; i < n4; i += nt) d[i] = s[i];
}
__device__ __forceinline__ void cpysn(float* __restrict__ dst, const float* __restrict__ src,
                                      int n, int t, int nt) {
  for (int i = t; i < n; i += nt) dst[i] = src[i];
}
__device__ __forceinline__ void stage36n(float* __restrict__ dst, const float* __restrict__ src,
                                         int nrows, int t, int nt) {
  int n4 = nrows * 8;
  for (int i = t; i < n4; i += nt) {
    int r = i >> 3, c = i & 7;
    *(float4*)&dst[r * 36 + c * 4] = *(const float4*)&src[r * 32 + c * 4];
  }
}

__device__ __forceinline__ void load32(const float* p, float* hv) {
#pragma unroll
  for (int c = 0; c < 8; c++) {
    float4 v = *(const float4*)&p[4 * c];
    hv[4 * c + 0] = v.x;
    hv[4 * c + 1] = v.y;
    hv[4 * c + 2] = v.z;
    hv[4 * c + 3] = v.w;
  }
}
// load 64 contiguous floats (16 float4) into registers
__device__ __forceinline__ void load64(const float* p, float* hv) {
#pragma unroll
  for (int c = 0; c < 16; c++) {
    float4 v = *(const float4*)&p[4 * c];
    hv[4 * c + 0] = v.x;
    hv[4 * c + 1] = v.y;
    hv[4 * c + 2] = v.z;
    hv[4 * c + 3] = v.w;
  }
}
__device__ __forceinline__ float dot32(const float* hv, const float* r) {
  float s = 0.f;
#pragma unroll
  for (int c = 0; c < 8; c++) {
    float4 w = *(const float4*)&r[4 * c];
    s += hv[4 * c + 0] * w.x + hv[4 * c + 1] * w.y + hv[4 * c + 2] * w.z + hv[4 * c + 3] * w.w;
  }
  return s;
}
// paired dot: acc.x = sum w[k]*hv[2k] (+bias), acc.y = sum w[k]*hv[2k+1]
// strict (w scalar) x (adjacent pair) pattern -> v_pk_fma_f32 bait
__device__ __forceinline__ float2 dotP(const float* hv2, const float* r, float bias) {
  float ax = bias, ay = 0.f;
#pragma unroll
  for (int c = 0; c < 8; c++) {
    float4 w = *(const float4*)&r[4 * c];
    ax += w.x * hv2[8 * c + 0];
    ay += w.x * hv2[8 * c + 1];
    ax += w.y * hv2[8 * c + 2];
    ay += w.y * hv2[8 * c + 3];
    ax += w.z * hv2[8 * c + 4];
    ay += w.z * hv2[8 * c + 5];
    ax += w.w * hv2[8 * c + 6];
    ay += w.w * hv2[8 * c + 7];
  }
  return make_float2(ax, ay);
}

// ---- quad (4-lane) E=2 fwd layer, 8 rows/lane: d kernel ----
__device__ __forceinline__ void coopFwd2(const float* Wb, const float* bh, const float* s0,
                                         const float* s1, float* d0, float* d1, int q) {
  float a0[32], a1[32];
  load32(s0, a0);
  load32(s1, a1);
#pragma unroll 2
  for (int m8 = 0; m8 < 8; m8++) {
    int j = q + 4 * m8;
    const float* r = Wb + j * 36;
    float z0 = bh[j], z1 = bh[j];
#pragma unroll
    for (int c = 0; c < 8; c++) {
      float4 w = *(const float4*)&r[4 * c];
      z0 += a0[4 * c + 0] * w.x + a0[4 * c + 1] * w.y + a0[4 * c + 2] * w.z + a0[4 * c + 3] * w.w;
      z1 += a1[4 * c + 0] * w.x + a1[4 * c + 1] * w.y + a1[4 * c + 2] * w.z + a1[4 * c + 3] * w.w;
    }
    d0[j] = sp1(z0);
    d1[j] = sp1(z1);
  }
}
// ---- octet (8-lane) E=2 fwd layer, 4 rows/lane: u kernel ----
__device__ __forceinline__ void coopFwd2O(const float* Wb, const float* bh, const float* s0,
                                          const float* s1, float* d0, float* d1, int o) {
  float a0[32], a1[32];
  load32(s0, a0);
  load32(s1, a1);
#pragma unroll
  for (int m4 = 0; m4 < 4; m4++) {
    int j = o + 8 * m4;
    const float* r = Wb + j * 36;
    float z0 = bh[j], z1 = bh[j];
#pragma unroll
    for (int c = 0; c < 8; c++) {
      float4 w = *(const float4*)&r[4 * c];
      z0 += a0[4 * c + 0] * w.x + a0[4 * c + 1] * w.y + a0[4 * c + 2] * w.z + a0[4 * c + 3] * w.w;
      z1 += a1[4 * c + 0] * w.x + a1[4 * c + 1] * w.y + a1[4 * c + 2] * w.z + a1[4 * c + 3] * w.w;
    }
    d0[j] = sp1(z0);
    d1[j] = sp1(z1);
  }
}
// ---- octet E=2 bwd matvec, 4 rows/lane ----
__device__ __forceinline__ void coopBwd2O(const float* Wb, const float* s0, const float* s1,
                                          float* d0, float* d1, int o) {
  float a0[32], a1[32];
  load32(s0, a0);
  load32(s1, a1);
#pragma unroll
  for (int m4 = 0; m4 < 4; m4++) {
    int k = o + 8 * m4;
    const float* r = Wb + k * 36;
    float z0 = 0.f, z1 = 0.f;
#pragma unroll
    for (int c = 0; c < 8; c++) {
      float4 w = *(const float4*)&r[4 * c];
      z0 += a0[4 * c + 0] * w.x + a0[4 * c + 1] * w.y + a0[4 * c + 2] * w.z + a0[4 * c + 3] * w.w;
      z1 += a1[4 * c + 0] * w.x + a1[4 * c + 1] * w.y + a1[4 * c + 2] * w.z + a1[4 * c + 3] * w.w;
    }
    d0[k] = z0;
    d1[k] = z1;
  }
}
// ---- octet E=1 fused layer on INTERLEAVED ht (pk-fma form): m kernel ----
__device__ __forceinline__ void coopFusedP(const float* Wb, const float* bh, float* ht, int o) {
  float hv[64];
  load64(ht, hv);
#pragma unroll
  for (int m4 = 0; m4 < 4; m4++) {
    int j = o + 8 * m4;
    float2 z = dotP(hv, Wb + j * 36, bh[j]);
    float hs, sg;
    sp_sig(z.x, hs, sg);
    *(float2*)&ht[2 * j] = make_float2(hs, z.y * sg);
  }
}

// ================= m kernel (octet E=1, 512 thr, 64 el, interleaved) ============
__global__ __launch_bounds__(512, 1) void mrole_kernel(const float* __restrict__ in,
                                                       const float* __restrict__ ws,
                                                       const float* __restrict__ m_b0,
                                                       const float* __restrict__ m_bh,
                                                       float* __restrict__ sc, int B) {
  __shared__ __align__(16) float L[LM_TOT];
  __shared__ int PIJ[21];
  const int t = threadIdx.x;
  cpy4n(L + L_W0P, ws + W0P_M, 64, t, 512);
  stage36n(L + L_WHT, ws + MWHT, 128, t, 512);
  stage36n(L + LM_WSYM, ws + WSYM, 21, t, 512);
  cpysn(L + LM_BSYM, ws + BSYM, 21, t, 512);
  cpysn(L + LM_B0, m_b0, 32, t, 512);
  cpysn(L + LM_BH, m_bh, 128, t, 512);
  if (t < 21) PIJ[t] = (IU21[t] << 3) | JU21[t];
  __syncthreads();

  const int el = t >> 3, o = t & 7;
  const int e = blockIdx.x * 64 + el;
  if (e >= B) return;
  const float* ip = in + (long)e * 18;
  const long Bl = B;

  float x0 = ip[0], x1 = ip[1], x2 = ip[2], x3 = ip[3], x4 = ip[4], x5 = ip[5];
  float d0 = ip[6], d1 = ip[7], d2 = ip[8], d3 = ip[9], d4 = ip[10], d5 = ip[11];
  if (o < 6) {
    L[LM_XD + el * 6 + o] = ip[6 + o];
    L[LM_TC + el * 6 + o] = 0.f;
  }
  float* ht = L + LM_HT + el * 76;
#pragma unroll
  for (int m4 = 0; m4 < 4; m4++) {
    int j = o + 8 * m4;
    float4 wa = *(const float4*)&L[L_W0P + j * 8];
    float4 wb = *(const float4*)&L[L_W0P + j * 8 + 4];
    float zh = L[LM_B0 + j] + x0 * wa.x + x1 * wa.y + x2 * wa.z + x3 * wa.w + x4 * wb.x + x5 * wb.y;
    float zt = d0 * wa.x + d1 * wa.y + d2 * wa.z + d3 * wa.w + d4 * wb.x + d5 * wb.y;
    float hs, sg;
    sp_sig(zh, hs, sg);
    *(float2*)&ht[2 * j] = make_float2(hs, zt * sg);
  }
#pragma unroll 1
  for (int l = 0; l < 4; l++) coopFusedP(L + L_WHT + l * 1152, L + LM_BH + l * 32, ht, o);
  float hv[64];
  load64(ht, hv);
#pragma unroll 1
  for (int mm = 0; mm < 3; mm++) {
    int p = o + 8 * mm;
    if (p < 21) {
      float2 vw = dotP(hv, L + LM_WSYM + p * 36, L[LM_BSYM + p]);
      sc[(long)p * Bl + e] = vw.x;
      int pij = PIJ[p];
      int iu = pij >> 3, ju = pij & 7;
      float xdj = L[LM_XD + el * 6 + ju];
      atomicAdd(&L[LM_TC + el * 6 + iu], vw.y * xdj);
      if (iu != ju) {
        float xdi = L[LM_XD + el * 6 + iu];
        atomicAdd(&L[LM_TC + el * 6 + ju], vw.y * xdi);
      }
    }
  }
  if (o < 6) sc[(long)(21 + o) * Bl + e] = L[LM_TC + el * 6 + o];
}

// ================= u kernel (octet E=2, 1024 thr, 256 el) =================
__global__ __launch_bounds__(1024, 1) void urole_kernel(
    const float* __restrict__ in, const float* __restrict__ ws, const float* __restrict__ u_W0,
    const float* __restrict__ u_b0, const float* __restrict__ u_Wh, const float* __restrict__ u_bh,
    const float* __restrict__ u_Wo, float* __restrict__ sc, int B) {
  __shared__ __align__(16) float L[LU_TOT];
  const int t = threadIdx.x;
  cpy4n(L + L_W0P, ws + W0P_U, 64, t, 1024);
  stage36n(L + L_WHT, ws + UWHT, 128, t, 1024);
  stage36n(L + LU_WHO, u_Wh, 128, t, 1024);
  cpy4n(L + LU_WO, u_Wo, 8, t, 1024);
  stage36n(L + LU_W0O, u_W0, 6, t, 1024);
  cpysn(L + LU_B0, u_b0, 32, t, 1024);
  cpysn(L + LU_BH, u_bh, 128, t, 1024);
  __syncthreads();

  const int oid = t >> 3, o = t & 7;
  const int e0 = blockIdx.x * 256 + oid;
  if (e0 >= B) return;
  const int e1 = e0 + 128;
  const bool has1 = e1 < B;
  const int el0 = oid, el1 = oid + 128;
  const float* ip0 = in + (long)e0 * 18;
  const float* ip1 = in + (long)(has1 ? e1 : e0) * 18;
  const long Bl = B;

  float X0[6], X1[6];
#pragma unroll
  for (int i = 0; i < 6; i++) {
    X0[i] = ip0[i];
    X1[i] = ip1[i];
  }
  float* S0 = L + LU_S + el0 * 36;
  float* S1 = L + LU_S + el1 * 36;
  float* HB0 = L + LU_HB + el0 * 36;
  float* HB1 = L + LU_HB + el1 * 36;
  float* HD0 = L + LU_HD + el0 * 36;
  float* HD1 = L + LU_HD + el1 * 36;
#pragma unroll
  for (int m4 = 0; m4 < 4; m4++) {
    int j = o + 8 * m4;
    float4 wa = *(const float4*)&L[L_W0P + j * 8];
    float4 wb = *(const float4*)&L[L_W0P + j * 8 + 4];
    float b = L[LU_B0 + j];
    S0[j] = sp1(b + X0[0] * wa.x + X0[1] * wa.y + X0[2] * wa.z + X0[3] * wa.w + X0[4] * wb.x +
                X0[5] * wb.y);
    S1[j] = sp1(b + X1[0] * wa.x + X1[1] * wa.y + X1[2] * wa.z + X1[3] * wa.w + X1[4] * wb.x +
                X1[5] * wb.y);
  }
  coopFwd2O(L + L_WHT + 0 * 1152, L + LU_BH + 0, S0, S1, HB0, HB1, o);
  coopFwd2O(L + L_WHT + 1 * 1152, L + LU_BH + 32, HB0, HB1, S0, S1, o);
  coopFwd2O(L + L_WHT + 2 * 1152, L + LU_BH + 64, S0, S1, HD0, HD1, o);
  coopFwd2O(L + L_WHT + 3 * 1152, L + LU_BH + 96, HD0, HD1, S0, S1, o);
#pragma unroll
  for (int m4 = 0; m4 < 4; m4++) {
    int j = o + 8 * m4;
    float wo = L[LU_WO + j];
    S0[j] = wo * sig_h(S0[j]);
    S1[j] = wo * sig_h(S1[j]);
  }
  coopBwd2O(L + LU_WHO + 3 * 1152, S0, S1, S0, S1, o);
#pragma unroll
  for (int m4 = 0; m4 < 4; m4++) {
    int j = o + 8 * m4;
    S0[j] = S0[j] * sig_h(HD0[j]);
    S1[j] = S1[j] * sig_h(HD1[j]);
  }
  coopBwd2O(L + LU_WHO + 2 * 1152, S0, S1, HD0, HD1, o);
  coopFwd2O(L + L_WHT + 1 * 1152, L + LU_BH + 32, HB0, HB1, S0, S1, o);  // recompute hc
#pragma unroll
  for (int m4 = 0; m4 < 4; m4++) {
    int j = o + 8 * m4;
    HD0[j] = HD0[j] * sig_h(S0[j]);
    HD1[j] = HD1[j] * sig_h(S1[j]);
  }
  coopBwd2O(L + LU_WHO + 1 * 1152, HD0, HD1, S0, S1, o);
#pragma unroll
  for (int m4 = 0; m4 < 4; m4++) {
    int j = o + 8 * m4;
    HB0[j] = S0[j] * sig_h(HB0[j]);
    HB1[j] = S1[j] * sig_h(HB1[j]);
  }
  coopBwd2O(L + LU_WHO + 0 * 1152, HB0, HB1, HD0, HD1, o);
#pragma unroll
  for (int m4 = 0; m4 < 4; m4++) {
    int j = o + 8 * m4;
    float4 wa = *(const float4*)&L[L_W0P + j * 8];
    float4 wb = *(const float4*)&L[L_W0P + j * 8 + 4];
    float b = L[LU_B0 + j];
    float a0 = sp1(b + X0[0] * wa.x + X0[1] * wa.y + X0[2] * wa.z + X0[3] * wa.w + X0[4] * wb.x +
                   X0[5] * wb.y);
    float a1 = sp1(b + X1[0] * wa.x + X1[1] * wa.y + X1[2] * wa.z + X1[3] * wa.w + X1[4] * wb.x +
                   X1[5] * wb.y);
    S0[j] = HD0[j] * sig_h(a0);
    S1[j] = HD1[j] * sig_h(a1);
  }
  if (o < 6) {
    float a0[32], a1[32];
    load32(S0, a0);
    load32(S1, a1);
    const float* r = L + LU_W0O + o * 36;
    float tp0 = 0.f, tp1 = 0.f;
#pragma unroll
    for (int c = 0; c < 8; c++) {
      float4 w = *(const float4*)&r[4 * c];
      tp0 += a0[4 * c + 0] * w.x + a0[4 * c + 1] * w.y + a0[4 * c + 2] * w.z + a0[4 * c + 3] * w.w;
      tp1 += a1[4 * c + 0] * w.x + a1[4 * c + 1] * w.y + a1[4 * c + 2] * w.z + a1[4 * c + 3] * w.w;
    }
    sc[(long)(27 + o) * Bl + e0] = tp0;
    if (has1) sc[(long)(27 + o) * Bl + e1] = tp1;
  }
}

// ================= d kernel (quad E=2, 256 thr, 128 el) =================
__global__ __launch_bounds__(256, 1) void drole_kernel(const float* __restrict__ in,
                                                       const float* __restrict__ ws,
                                                       const float* __restrict__ d_b0,
                                                       const float* __restrict__ d_bh,
                                                       const float* __restrict__ d_bo,
                                                       float* __restrict__ sc, int B) {
  __shared__ __align__(16) float L[LD_TOT];
  const int t = threadIdx.x;
  cpy4n(L + L_W0P, ws + W0P_D, 64, t, 256);
  stage36n(L + L_WHT, ws + DWHT, 128, t, 256);
  stage36n(L + LD_WOT, ws + DWOT, 36, t, 256);
  cpysn(L + LD_B0, d_b0, 32, t, 256);
  cpysn(L + LD_BH, d_bh, 128, t, 256);
  cpysn(L + LD_BO, d_bo, 36, t, 256);
  __syncthreads();

  const int qid = t >> 2, q = t & 3;
  const int e0 = blockIdx.x * 128 + qid;
  if (e0 >= B) return;
  const int e1 = e0 + 64;
  const bool has1 = e1 < B;
  const int el0 = qid, el1 = qid + 64;
  const float* ip0 = in + (long)e0 * 18;
  const float* ip1 = in + (long)(has1 ? e1 : e0) * 18;
  const long Bl = B;

  float X0[6], X1[6];
#pragma unroll
  for (int i = 0; i < 6; i++) {
    X0[i] = ip0[i];
    X1[i] = ip1[i];
  }
  float* S0 = L + LD_S + el0 * 36;
  float* S1 = L + LD_S + el1 * 36;
#pragma unroll 2
  for (int m8 = 0; m8 < 8; m8++) {
    int j = q + 4 * m8;
    float4 wa = *(const float4*)&L[L_W0P + j * 8];
    float4 wb = *(const float4*)&L[L_W0P + j * 8 + 4];
    float b = L[LD_B0 + j];
    S0[j] = sp1(b + X0[0] * wa.x + X0[1] * wa.y + X0[2] * wa.z + X0[3] * wa.w + X0[4] * wb.x +
                X0[5] * wb.y);
    S1[j] = sp1(b + X1[0] * wa.x + X1[1] * wa.y + X1[2] * wa.z + X1[3] * wa.w + X1[4] * wb.x +
                X1[5] * wb.y);
  }
#pragma unroll 1
  for (int l = 0; l < 4; l++)
    coopFwd2(L + L_WHT + l * 1152, L + LD_BH + l * 32, S0, S1, S0, S1, q);
  float a0[32], a1[32];
  load32(S0, a0);
  load32(S1, a1);
#pragma unroll 1
  for (int mm = 0; mm < 2; mm++) {
    int i = q + 4 * mm;
    if (i < 6) {
      float td0 = 0.f, td1 = 0.f;
#pragma unroll 1
      for (int c = 0; c < 6; c++) {
        const float* r = L + LD_WOT + (i * 6 + c) * 36;
        float b = L[LD_BO + i * 6 + c];
        float v0 = b, v1 = b;
#pragma unroll
        for (int cc = 0; cc < 8; cc++) {
          float4 w = *(const float4*)&r[4 * cc];
          v0 += a0[4 * cc + 0] * w.x + a0[4 * cc + 1] * w.y + a0[4 * cc + 2] * w.z +
                a0[4 * cc + 3] * w.w;
          v1 += a1[4 * cc + 0] * w.x + a1[4 * cc + 1] * w.y + a1[4 * cc + 2] * w.z +
                a1[4 * cc + 3] * w.w;
        }
        td0 += v0 * ip0[6 + c];
        td1 += v1 * ip1[6 + c];
      }
      sc[(long)(33 + i) * Bl + e0] = td0;
      if (has1) sc[(long)(33 + i) * Bl + e1] = td1;
    }
  }
}

// ---------------- combine + solve (unchanged) ----------------
__global__ __launch_bounds__(256) void combine_kernel(const float* __restrict__ in,
                                                      const float* __restrict__ A,
                                                      const float* __restrict__ sc,
                                                      float* __restrict__ out, int B) {
  int b = blockIdx.x * 256 + threadIdx.x;
  if (b >= B) return;
  const long Bl = B;
  const float* ip = in + (long)b * 18;
  float te[6];
  {
    float tv[6];
#pragma unroll
    for (int i = 0; i < 6; i++) tv[i] = ip[12 + i];
#pragma unroll
    for (int i = 0; i < 6; i++) {
      float s = 0.f;
#pragma unroll
      for (int j = 0; j < 6; j++) s += tv[j] * A[j * 6 + i];
      te[i] = s;
    }
  }
  float Ms[6][6], r[6], y[6];
  {
    int idx = 0;
#pragma unroll
    for (int i = 0; i < 6; i++)
#pragma unroll
      for (int j = i; j < 6; j++) {
        float v = sc[idx * Bl + b];
        Ms[i][j] = v;
        Ms[j][i] = v;
        idx++;
      }
  }
#pragma unroll
  for (int i = 0; i < 6; i++)
    r[i] = te[i] - sc[(21 + i) * Bl + b] - sc[(27 + i) * Bl + b] - sc[(33 + i) * Bl + b];

#pragma unroll
  for (int k = 0; k < 6; k++) {
#pragma unroll
    for (int rr = k + 1; rr < 6; rr++) {
      bool c = fabsf(Ms[rr][k]) > fabsf(Ms[k][k]);
#pragma unroll
      for (int j = 0; j < 6; j++) {
        float a = Ms[k][j], bb = Ms[rr][j];
        Ms[k][j] = c ? bb : a;
        Ms[rr][j] = c ? a : bb;
      }
      float a = r[k], bb = r[rr];
      r[k] = c ? bb : a;
      r[rr] = c ? a : bb;
    }
    float piv = Ms[k][k];
#pragma unroll
    for (int rr = k + 1; rr < 6; rr++) {
      float f = Ms[rr][k] / piv;
#pragma unroll
      for (int j = k; j < 6; j++) Ms[rr][j] -= f * Ms[k][j];
      r[rr] -= f * r[k];
    }
  }
#pragma unroll
  for (int ki = 5; ki >= 0; ki--) {
    float v = r[ki];
#pragma unroll
    for (int j = ki + 1; j < 6; j++) v -= Ms[ki][j] * y[j];
    y[ki] = v / Ms[ki][ki];
  }
  float* op = out + (long)b * 6;
#pragma unroll
  for (int i = 0; i < 6; i++) op[i] = y[i];
}

// ---------------- fallback monolithic kernel ----------------
__device__ __forceinline__ void fwd_layer(const float* __restrict__ Wb,
                                          const float* __restrict__ bh,
                                          const float* __restrict__ hin, float* __restrict__ hout) {
#pragma unroll
  for (int j = 0; j < 32; j++) {
    const float* r = Wb + j * 32;
    float z = bh[j];
#pragma unroll
    for (int k = 0; k < 32; k++) z += hin[k] * r[k];
    hout[j] = sp1(z);
  }
}
__device__ __forceinline__ void m_layer(const float* __restrict__ Wb, const float* __restrict__ bh,
                                        float* __restrict__ h, const float* __restrict__ tin,
                                        float* __restrict__ tout) {
#pragma unroll
  for (int j = 0; j < 32; j++) {
    const float* r = Wb + j * 32;
    float z = bh[j];
#pragma unroll
    for (int k = 0; k < 32; k++) z += h[k] * r[k];
    tout[j] = z;
  }
#pragma unroll
  for (int j = 0; j < 32; j++) {
    const float* r = Wb + j * 32;
    float z = 0.f;
#pragma unroll
    for (int k = 0; k < 32; k++) z += tin[k] * r[k];
    float hs, sg;
    sp_sig(tout[j], hs, sg);
    h[j] = hs;
    tout[j] = z * sg;
  }
}
__device__ __forceinline__ void bwd_mv(const float* __restrict__ Worig,
                                       const float* __restrict__ gin, float* __restrict__ gout) {
#pragma unroll
  for (int k = 0; k < 32; k++) {
    const float* r = Worig + k * 32;
    float s = 0.f;
#pragma unroll
    for (int j = 0; j < 32; j++) s += r[j] * gin[j];
    gout[k] = s;
  }
}

__global__ __launch_bounds__(64, 1) void lnn_kernel(
    const float* __restrict__ in, const float* __restrict__ A, const float* __restrict__ ws,
    const float* __restrict__ m_b0, const float* __restrict__ m_bh, const float* __restrict__ m_bo,
    const float* __restrict__ u_W0, const float* __restrict__ u_b0, const float* __restrict__ u_Wh,
    const float* __restrict__ u_bh, const float* __restrict__ u_Wo,
    const float* __restrict__ d_b0, const float* __restrict__ d_bh, const float* __restrict__ d_bo,
    float* __restrict__ out, int B) {
  int b = blockIdx.x * 64 + threadIdx.x;
  if (b >= B) return;
  const float* ip = in + (long)b * 18;
  float x[6], xd[6], te[6];
#pragma unroll
  for (int i = 0; i < 6; i++) {
    x[i] = ip[i];
    xd[i] = ip[6 + i];
  }
  {
    float tv[6];
#pragma unroll
    for (int i = 0; i < 6; i++) tv[i] = ip[12 + i];
#pragma unroll
    for (int i = 0; i < 6; i++) {
      float s = 0.f;
#pragma unroll
      for (int j = 0; j < 6; j++) s += tv[j] * A[j * 6 + i];
      te[i] = s;
    }
  }
  float td[6] = {0, 0, 0, 0, 0, 0};
  {
    float h[32], zn[32];
    const float* w0 = ws + DW0T;
#pragma unroll
    for (int j = 0; j < 32; j++) {
      float z = d_b0[j];
#pragma unroll
      for (int k = 0; k < 6; k++) z += x[k] * w0[j * 6 + k];
      h[j] = sp1(z);
    }
    fwd_layer(ws + DWHT + 0 * 1024, d_bh + 0, h, zn);
    fwd_layer(ws + DWHT + 1 * 1024, d_bh + 32, zn, h);
    fwd_layer(ws + DWHT + 2 * 1024, d_bh + 64, h, zn);
    fwd_layer(ws + DWHT + 3 * 1024, d_bh + 96, zn, h);
    const float* wo = ws + DWOT;
#pragma unroll
    for (int o = 0; o < 36; o++) {
      float v = d_bo[o];
#pragma unroll
      for (int k = 0; k < 32; k++) v += h[k] * wo[o * 32 + k];
      td[o / 6] += v * xd[o % 6];
    }
  }
  float tp[6] = {0, 0, 0, 0, 0, 0};
  {
    float hb[32], hd[32], s[32], r2[32];
    const float* w0 = ws + UW0T;
#pragma unroll
    for (int j = 0; j < 32; j++) {
      float z = u_b0[j];
#pragma unroll
      for (int k = 0; k < 6; k++) z += x[k] * w0[j * 6 + k];
      s[j] = sp1(z);
    }
    fwd_layer(ws + UWHT + 0 * 1024, u_bh + 0, s, hb);
    fwd_layer(ws + UWHT + 1 * 1024, u_bh + 32, hb, s);
    fwd_layer(ws + UWHT + 2 * 1024, u_bh + 64, s, hd);
    fwd_layer(ws + UWHT + 3 * 1024, u_bh + 96, hd, s);
#pragma unroll
    for (int j = 0; j < 32; j++) s[j] = u_Wo[j] * sig_h(s[j]);
    bwd_mv(u_Wh + 3 * 1024, s, r2);
#pragma unroll
    for (int j = 0; j < 32; j++) s[j] = r2[j] * sig_h(hd[j]);
    bwd_mv(u_Wh + 2 * 1024, s, hd);
    fwd_layer(ws + UWHT + 1 * 1024, u_bh + 32, hb, s);
#pragma unroll
    for (int j = 0; j < 32; j++) r2[j] = hd[j] * sig_h(s[j]);
    bwd_mv(u_Wh + 1 * 1024, r2, s);
#pragma unroll
    for (int j = 0; j < 32; j++) r2[j] = s[j] * sig_h(hb[j]);
    bwd_mv(u_Wh + 0 * 1024, r2, hb);
#pragma unroll
    for (int j = 0; j < 32; j++) {
      float z = u_b0[j];
#pragma unroll
      for (int k = 0; k < 6; k++) z += x[k] * w0[j * 6 + k];
      s[j] = sp1(z);
    }
#pragma unroll
    for (int j = 0; j < 32; j++) s[j] = hb[j] * sig_h(s[j]);
#pragma unroll
    for (int i = 0; i < 6; i++) {
      float t = 0.f;
#pragma unroll
      for (int j = 0; j < 32; j++) t += u_W0[i * 32 + j] * s[j];
      tp[i] = t;
    }
  }
  float Ms[6][6], tc[6];
  {
    float h[32], t[32], zn[32];
    const float* w0 = ws + MW0T;
#pragma unroll
    for (int j = 0; j < 32; j++) {
      float zh = m_b0[j], zt = 0.f;
#pragma unroll
      for (int k = 0; k < 6; k++) {
        zh += x[k] * w0[j * 6 + k];
        zt += xd[k] * w0[j * 6 + k];
      }
      float hs, sg;
      sp_sig(zh, hs, sg);
      h[j] = hs;
      t[j] = zt * sg;
    }
    m_layer(ws + MWHT + 0 * 1024, m_bh + 0, h, t, zn);
    m_layer(ws + MWHT + 1 * 1024, m_bh + 32, h, zn, t);
    m_layer(ws + MWHT + 2 * 1024, m_bh + 64, h, t, zn);
    m_layer(ws + MWHT + 3 * 1024, m_bh + 96, h, zn, t);
    const float* wo = ws + MWOT;
    float Msv[21];
    int idx = 0;
#pragma unroll
    for (int i = 0; i < 6; i++) tc[i] = 0.f;
#pragma unroll
    for (int i = 0; i < 6; i++)
#pragma unroll
      for (int j = i; j < 6; j++) {
        const float* r = wo + (i * 6 + j) * 32;
        float v = m_bo[i * 6 + j], w = 0.f;
#pragma unroll
        for (int k = 0; k < 32; k++) {
          v += h[k] * r[k];
          w += t[k] * r[k];
        }
        if (i != j) {
          const float* rr = wo + (j * 6 + i) * 32;
          float v2 = m_bo[j * 6 + i], w2 = 0.f;
#pragma unroll
          for (int k = 0; k < 32; k++) {
            v2 += h[k] * rr[k];
            w2 += t[k] * rr[k];
          }
          v = 0.5f * (v + v2);
          w = 0.5f * (w + w2);
        }
        Msv[idx] = v;
        tc[i] += w * xd[j];
        if (j != i) tc[j] += w * xd[i];
        idx++;
      }
    idx = 0;
#pragma unroll
    for (int i = 0; i < 6; i++)
#pragma unroll
      for (int j = i; j < 6; j++) {
        Ms[i][j] = Msv[idx];
        Ms[j][i] = Msv[idx];
        idx++;
      }
  }
  float r[6], y[6];
#pragma unroll
  for (int i = 0; i < 6; i++) r[i] = te[i] - tc[i] - tp[i] - td[i];
#pragma unroll
  for (int k = 0; k < 6; k++) {
#pragma unroll
    for (int rr = k + 1; rr < 6; rr++) {
      bool c = fabsf(Ms[rr][k]) > fabsf(Ms[k][k]);
#pragma unroll
      for (int j = 0; j < 6; j++) {
        float a = Ms[k][j], bb = Ms[rr][j];
        Ms[k][j] = c ? bb : a;
        Ms[rr][j] = c ? a : bb;
      }
      float a = r[k], bb = r[rr];
      r[k] = c ? bb : a;
      r[rr] = c ? a : bb;
    }
    float piv = Ms[k][k];
#pragma unroll
    for (int rr = k + 1; rr < 6; rr++) {
      float f = Ms[rr][k] / piv;
#pragma unroll
      for (int j = k; j < 6; j++) Ms[rr][j] -= f * Ms[k][j];
      r[rr] -= f * r[k];
    }
  }
#pragma unroll
  for (int ki = 5; ki >= 0; ki--) {
    float v = r[ki];
#pragma unroll
    for (int j = ki + 1; j < 6; j++) v -= Ms[ki][j] * y[j];
    y[ki] = v / Ms[ki][ki];
  }
  float* op = out + (long)b * 6;
#pragma unroll
  for (int i = 0; i < 6; i++) op[i] = y[i];
}

extern "C" void kernel_launch(void* const* d_in, const int* in_sizes, int n_in, void* d_out,
                              int out_size, void* d_ws, size_t ws_size, hipStream_t stream) {
  const float* inputs = (const float*)d_in[0];
  const float* A = (const float*)d_in[1];
  const float* m_W0 = (const float*)d_in[2];
  const float* m_b0 = (const float*)d_in[3];
  const float* m_Wh = (const float*)d_in[4];
  const float* m_bh = (const float*)d_in[5];
  const float* m_Wo = (const float*)d_in[6];
  const float* m_bo = (const float*)d_in[7];
  const float* u_W0 = (const float*)d_in[8];
  const float* u_b0 = (const float*)d_in[9];
  const float* u_Wh = (const float*)d_in[10];
  const float* u_bh = (const float*)d_in[11];
  const float* u_Wo = (const float*)d_in[12];
  const float* d_W0 = (const float*)d_in[14];
  const float* d_b0 = (const float*)d_in[15];
  const float* d_Wh = (const float*)d_in[16];
  const float* d_bh = (const float*)d_in[17];
  const float* d_Wo = (const float*)d_in[18];
  const float* d_bo = (const float*)d_in[19];

  float* ws = (float*)d_ws;
  float* out = (float*)d_out;
  int B = in_sizes[0] / 18;

  prep_kernel<<<16, 256, 0, stream>>>(m_W0, m_Wh, m_Wo, m_bo, u_W0, u_Wh, u_Wo, d_W0, d_Wh, d_Wo,
                                      ws);

  size_t need = (size_t)(SC_BASE + (size_t)B * 39) * 4;
  if (ws_size >= need) {
    float* sc = ws + SC_BASE;
    int nb_m = (B + 63) / 64;  // v12 geometry: 1024 blocks, 3/CU resident
    int nb_d = (B + 127) / 128;
    int nb_u = (B + 255) / 256;
    mrole_kernel<<<nb_m, 512, 0, stream>>>(inputs, ws, m_b0, m_bh, sc, B);
    urole_kernel<<<nb_u, 1024, 0, stream>>>(inputs, ws, u_W0, u_b0, u_Wh, u_bh, u_Wo, sc, B);
    drole_kernel<<<nb_d, 256, 0, stream>>>(inputs, ws, d_b0, d_bh, d_bo, sc, B);
    combine_kernel<<<(B + 255) / 256, 256, 0, stream>>>(inputs, A, sc, out, B);
  } else {
    lnn_kernel<<<(B + 63) / 64, 64, 0, stream>>>(inputs, A, ws, m_b0, m_bh, m_bo, u_W0, u_b0, u_Wh,
                                                 u_bh, u_Wo, d_b0, d_bh, d_bo, out, B);
  }
}

// Round 14
// 106.724 us; speedup vs baseline: 1.0970x; 1.0240x over previous
//
#include <hip/hip_runtime.h>

// LnnDynamics v15: m pair-decomposition (2 lanes/element).
// v14 closed the model: m is ds_read_b128-THROUGHPUT-bound. Count:
// 384 b128/el-layer (256 weights + 128 acts; acts re-read by all 8
// octet lanes) x ~6 layers x 65536 el x ~12cyc/b128 / 256 CU ~= 52us
// = measured 50us. Also VGPR=56 < 64: allocator chased 8 waves/SIMD
// and demoted hv[64] to per-row LDS re-reads.
// v15: 2 lanes/el -> act redundancy 8x->2x (384->~288 reads/el-layer);
// 512thr = 256 el/block, ~111KB LDS -> 1 block/CU (256 blocks, no
// tail) -> 2 waves/SIMD -> VGPR budget 256 -> hv stays resident.
// u (octet E=2, 1024thr), d (quad E=2), combine, prep unchanged.
// Scratch sc SoA: sc[f*B+b], f: 0-20 Ms, 21-26 tc, 27-32 tp, 33-38 td.

#define NQ 6
#define HID 32
#define NHID 4

// workspace float offsets (built by prep_kernel)
#define MW0T 0
#define UW0T 192
#define DW0T 384
#define MWHT 576
#define UWHT (576 + 4096)
#define DWHT (576 + 8192)
#define MWOT (576 + 12288)
#define DWOT (MWOT + 1152)
#define UWOT (DWOT + 1152)
#define W0P_M 15200
#define W0P_U 15488
#define W0P_D 15744
#define WSYM 16000
#define BSYM 16672
#define SC_BASE 16896

// ---- common LDS slots ----
#define L_W0P 0    // 256 (stride-8 padded W0 rows)
#define L_WHT 256  // 128 rows * 36 -> 4864 (transposed fwd Wh)
// m kernel (pair E=1, 512 thr, 256 el, interleaved ht):
#define LM_WSYM 4864  // 21*36 -> 5620
#define LM_BSYM 5620
#define LM_B0 5644
#define LM_BH 5676  // -> 5804
#define LM_HT 5804   // 256 el * 76 -> 25260
#define LM_XD 25260  // 256*6 -> 26796
#define LM_TC 26796  // -> 28332
#define LM_TOT 28336  // 113.3 KB -> 1 block/CU (8 waves, 2/SIMD)
// u kernel (octet E=2, 1024 thr, 256 el):
#define LU_WHO 4864  // 128*36 -> 9472 (orig-layout Wh for bwd)
#define LU_WO 9472   // 32
#define LU_W0O 9504  // 6*36 -> 9720
#define LU_B0 9720
#define LU_BH 9752  // -> 9880
#define LU_S 9880    // 256*36 -> 19096
#define LU_HB 19096  // -> 28312
#define LU_HD 28312  // -> 37528
#define LU_TOT 37528  // 150.1 KB -> 1 block/CU (16 waves)
// d kernel (quad E=2, 256 thr, 128 el):
#define LD_WOT 4864  // 36*36 -> 6160
#define LD_B0 6160
#define LD_BH 6192
#define LD_BO 6320  // -> 6356
#define LD_S 6356   // 128*36 -> 10964
#define LD_TOT 10964  // 43.9 KB -> 3 blocks/CU

__device__ const int IU21[21] = {0, 0, 0, 0, 0, 0, 1, 1, 1, 1, 1, 2, 2, 2, 2, 3, 3, 3, 4, 4, 5};
__device__ const int JU21[21] = {0, 1, 2, 3, 4, 5, 1, 2, 3, 4, 5, 2, 3, 4, 5, 3, 4, 5, 4, 5, 5};

__global__ void prep_kernel(const float* __restrict__ mW0, const float* __restrict__ mWh,
                            const float* __restrict__ mWo, const float* __restrict__ m_bo,
                            const float* __restrict__ uW0, const float* __restrict__ uWh,
                            const float* __restrict__ uWo, const float* __restrict__ dW0,
                            const float* __restrict__ dWh, const float* __restrict__ dWo,
                            float* __restrict__ ws) {
  int t = blockIdx.x * blockDim.x + threadIdx.x;
  if (t < 192) {
    int j = t / 6, k = t % 6;
    ws[MW0T + t] = mW0[k * HID + j];
    ws[UW0T + t] = uW0[k * HID + j];
    ws[DW0T + t] = dW0[k * HID + j];
  }
  if (t < 256) {  // padded W0p[j*8+k]
    int j = t >> 3, k = t & 7;
    float vm = 0.f, vu = 0.f, vd = 0.f;
    if (k < 6) {
      vm = mW0[k * HID + j];
      vu = uW0[k * HID + j];
      vd = dW0[k * HID + j];
    }
    ws[W0P_M + t] = vm;
    ws[W0P_U + t] = vu;
    ws[W0P_D + t] = vd;
  }
  if (t < 4096) {
    int l = t >> 10, j = (t >> 5) & 31, k = t & 31;
    int src = l * 1024 + k * 32 + j;
    ws[MWHT + t] = mWh[src];
    ws[UWHT + t] = uWh[src];
    ws[DWHT + t] = dWh[src];
  }
  if (t < 1152) {
    int o = t / 32, k = t % 32;
    ws[MWOT + t] = mWo[k * 36 + o];
    ws[DWOT + t] = dWo[k * 36 + o];
  }
  if (t < 32) ws[UWOT + t] = uWo[t];
  if (t < 672) {
    int p = t >> 5, k = t & 31;
    int i = IU21[p], j = JU21[p];
    ws[WSYM + t] = 0.5f * (mWo[k * 36 + i * 6 + j] + mWo[k * 36 + j * 6 + i]);
  }
  if (t < 21) {
    int i = IU21[t], j = JU21[t];
    ws[BSYM + t] = 0.5f * (m_bo[i * 6 + j] + m_bo[j * 6 + i]);
  }
}

__device__ __forceinline__ float sp1(float z) {
  return fmaxf(z, 0.f) + __logf(1.f + __expf(-fabsf(z)));
}
__device__ __forceinline__ void sp_sig(float z, float& hs, float& sg) {
  float e = __expf(-fabsf(z));
  float d = __builtin_amdgcn_rcpf(1.f + e);
  hs = fmaxf(z, 0.f) + __logf(1.f + e);
  sg = (z >= 0.f ? 1.f : e) * d;
}
__device__ __forceinline__ float sig_h(float h) { return 1.f - __expf(-h); }

__device__ __forceinline__ void cpy4n(float* __restrict__ dst, const float* __restrict__ src,
                                      int n4, int t, int nt) {
  const float4* s = (const float4*)src;
  float4* d = (float4*)dst;
  for (int i = t; i < n4; i += nt) d[i] = s[i];
}
__device__ __forceinline__ void cpysn(float* __restrict__ dst, const float* __restrict__ src,
                                      int n, int t, int nt) {
  for (int i = t; i < n; i += nt) dst[i] = src[i];
}
__device__ __forceinline__ void stage36n(float* __restrict__ dst, const float* __restrict__ src,
                                         int nrows, int t, int nt) {
  int n4 = nrows * 8;
  for (int i = t; i < n4; i += nt) {
    int r = i >> 3, c = i & 7;
    *(float4*)&dst[r * 36 + c * 4] = *(const float4*)&src[r * 32 + c * 4];
  }
}

__device__ __forceinline__ void load32(const float* p, float* hv) {
#pragma unroll
  for (int c = 0; c < 8; c++) {
    float4 v = *(const float4*)&p[4 * c];
    hv[4 * c + 0] = v.x;
    hv[4 * c + 1] = v.y;
    hv[4 * c + 2] = v.z;
    hv[4 * c + 3] = v.w;
  }
}
// load 64 contiguous floats (16 float4) into registers
__device__ __forceinline__ void load64(const float* p, float* hv) {
#pragma unroll
  for (int c = 0; c < 16; c++) {
    float4 v = *(const float4*)&p[4 * c];
    hv[4 * c + 0] = v.x;
    hv[4 * c + 1] = v.y;
    hv[4 * c + 2] = v.z;
    hv[4 * c + 3] = v.w;
  }
}
// paired dot: acc.x = sum w[k]*hv[2k] (+bias), acc.y = sum w[k]*hv[2k+1]
// strict (w scalar) x (adjacent pair) pattern -> v_pk_fma_f32 bait
__device__ __forceinline__ float2 dotP(const float* hv2, const float* r, float bias) {
  float ax = bias, ay = 0.f;
#pragma unroll
  for (int c = 0; c < 8; c++) {
    float4 w = *(const float4*)&r[4 * c];
    ax += w.x * hv2[8 * c + 0];
    ay += w.x * hv2[8 * c + 1];
    ax += w.y * hv2[8 * c + 2];
    ay += w.y * hv2[8 * c + 3];
    ax += w.z * hv2[8 * c + 4];
    ay += w.z * hv2[8 * c + 5];
    ax += w.w * hv2[8 * c + 6];
    ay += w.w * hv2[8 * c + 7];
  }
  return make_float2(ax, ay);
}

// ---- quad (4-lane) E=2 fwd layer, 8 rows/lane: d kernel ----
__device__ __forceinline__ void coopFwd2(const float* Wb, const float* bh, const float* s0,
                                         const float* s1, float* d0, float* d1, int q) {
  float a0[32], a1[32];
  load32(s0, a0);
  load32(s1, a1);
#pragma unroll 2
  for (int m8 = 0; m8 < 8; m8++) {
    int j = q + 4 * m8;
    const float* r = Wb + j * 36;
    float z0 = bh[j], z1 = bh[j];
#pragma unroll
    for (int c = 0; c < 8; c++) {
      float4 w = *(const float4*)&r[4 * c];
      z0 += a0[4 * c + 0] * w.x + a0[4 * c + 1] * w.y + a0[4 * c + 2] * w.z + a0[4 * c + 3] * w.w;
      z1 += a1[4 * c + 0] * w.x + a1[4 * c + 1] * w.y + a1[4 * c + 2] * w.z + a1[4 * c + 3] * w.w;
    }
    d0[j] = sp1(z0);
    d1[j] = sp1(z1);
  }
}
// ---- octet (8-lane) E=2 fwd layer, 4 rows/lane: u kernel ----
__device__ __forceinline__ void coopFwd2O(const float* Wb, const float* bh, const float* s0,
                                          const float* s1, float* d0, float* d1, int o) {
  float a0[32], a1[32];
  load32(s0, a0);
  load32(s1, a1);
#pragma unroll
  for (int m4 = 0; m4 < 4; m4++) {
    int j = o + 8 * m4;
    const float* r = Wb + j * 36;
    float z0 = bh[j], z1 = bh[j];
#pragma unroll
    for (int c = 0; c < 8; c++) {
      float4 w = *(const float4*)&r[4 * c];
      z0 += a0[4 * c + 0] * w.x + a0[4 * c + 1] * w.y + a0[4 * c + 2] * w.z + a0[4 * c + 3] * w.w;
      z1 += a1[4 * c + 0] * w.x + a1[4 * c + 1] * w.y + a1[4 * c + 2] * w.z + a1[4 * c + 3] * w.w;
    }
    d0[j] = sp1(z0);
    d1[j] = sp1(z1);
  }
}
// ---- octet E=2 bwd matvec, 4 rows/lane ----
__device__ __forceinline__ void coopBwd2O(const float* Wb, const float* s0, const float* s1,
                                          float* d0, float* d1, int o) {
  float a0[32], a1[32];
  load32(s0, a0);
  load32(s1, a1);
#pragma unroll
  for (int m4 = 0; m4 < 4; m4++) {
    int k = o + 8 * m4;
    const float* r = Wb + k * 36;
    float z0 = 0.f, z1 = 0.f;
#pragma unroll
    for (int c = 0; c < 8; c++) {
      float4 w = *(const float4*)&r[4 * c];
      z0 += a0[4 * c + 0] * w.x + a0[4 * c + 1] * w.y + a0[4 * c + 2] * w.z + a0[4 * c + 3] * w.w;
      z1 += a1[4 * c + 0] * w.x + a1[4 * c + 1] * w.y + a1[4 * c + 2] * w.z + a1[4 * c + 3] * w.w;
    }
    d0[k] = z0;
    d1[k] = z1;
  }
}
// ---- pair E=1 fused layer on INTERLEAVED ht (pk-fma form): m kernel ----
// 16 rows/lane; hv[64] stays register-resident at 2 waves/SIMD budget.
__device__ __forceinline__ void coopFusedP2(const float* Wb, const float* bh, float* ht, int o) {
  float hv[64];
  load64(ht, hv);
#pragma unroll 2
  for (int m16 = 0; m16 < 16; m16++) {
    int j = o + 2 * m16;
    float2 z = dotP(hv, Wb + j * 36, bh[j]);
    float hs, sg;
    sp_sig(z.x, hs, sg);
    *(float2*)&ht[2 * j] = make_float2(hs, z.y * sg);
  }
}

// ============ m kernel (pair E=1, 512 thr, 256 el, interleaved) ============
__global__ __launch_bounds__(512, 1) void mrole_kernel(const float* __restrict__ in,
                                                       const float* __restrict__ ws,
                                                       const float* __restrict__ m_b0,
                                                       const float* __restrict__ m_bh,
                                                       float* __restrict__ sc, int B) {
  __shared__ __align__(16) float L[LM_TOT];
  __shared__ int PIJ[21];
  const int t = threadIdx.x;
  cpy4n(L + L_W0P, ws + W0P_M, 64, t, 512);
  stage36n(L + L_WHT, ws + MWHT, 128, t, 512);
  stage36n(L + LM_WSYM, ws + WSYM, 21, t, 512);
  cpysn(L + LM_BSYM, ws + BSYM, 21, t, 512);
  cpysn(L + LM_B0, m_b0, 32, t, 512);
  cpysn(L + LM_BH, m_bh, 128, t, 512);
  if (t < 21) PIJ[t] = (IU21[t] << 3) | JU21[t];
  __syncthreads();

  const int el = t >> 1, o = t & 1;
  const int e = blockIdx.x * 256 + el;
  if (e >= B) return;
  const float* ip = in + (long)e * 18;
  const long Bl = B;

  float x0 = ip[0], x1 = ip[1], x2 = ip[2], x3 = ip[3], x4 = ip[4], x5 = ip[5];
  float d0 = ip[6], d1 = ip[7], d2 = ip[8], d3 = ip[9], d4 = ip[10], d5 = ip[11];
  // each of the 2 lanes writes 3 XD/TC slots: o, o+2, o+4
  L[LM_XD + el * 6 + o] = ip[6 + o];
  L[LM_XD + el * 6 + o + 2] = ip[8 + o];
  L[LM_XD + el * 6 + o + 4] = ip[10 + o];
  L[LM_TC + el * 6 + o] = 0.f;
  L[LM_TC + el * 6 + o + 2] = 0.f;
  L[LM_TC + el * 6 + o + 4] = 0.f;
  float* ht = L + LM_HT + el * 76;
  // first layer: 16 rows per lane (j = o + 2*m16)
#pragma unroll 2
  for (int m16 = 0; m16 < 16; m16++) {
    int j = o + 2 * m16;
    float4 wa = *(const float4*)&L[L_W0P + j * 8];
    float4 wb = *(const float4*)&L[L_W0P + j * 8 + 4];
    float zh = L[LM_B0 + j] + x0 * wa.x + x1 * wa.y + x2 * wa.z + x3 * wa.w + x4 * wb.x + x5 * wb.y;
    float zt = d0 * wa.x + d1 * wa.y + d2 * wa.z + d3 * wa.w + d4 * wb.x + d5 * wb.y;
    float hs, sg;
    sp_sig(zh, hs, sg);
    *(float2*)&ht[2 * j] = make_float2(hs, zt * sg);
  }
#pragma unroll 1
  for (int l = 0; l < 4; l++) coopFusedP2(L + L_WHT + l * 1152, L + LM_BH + l * 32, ht, o);
  float hv[64];
  load64(ht, hv);
#pragma unroll 1
  for (int mm = 0; mm < 11; mm++) {
    int p = o + 2 * mm;
    if (p < 21) {
      float2 vw = dotP(hv, L + LM_WSYM + p * 36, L[LM_BSYM + p]);
      sc[(long)p * Bl + e] = vw.x;
      int pij = PIJ[p];
      int iu = pij >> 3, ju = pij & 7;
      float xdj = L[LM_XD + el * 6 + ju];
      atomicAdd(&L[LM_TC + el * 6 + iu], vw.y * xdj);
      if (iu != ju) {
        float xdi = L[LM_XD + el * 6 + iu];
        atomicAdd(&L[LM_TC + el * 6 + ju], vw.y * xdi);
      }
    }
  }
  sc[(long)(21 + o) * Bl + e] = L[LM_TC + el * 6 + o];
  sc[(long)(23 + o) * Bl + e] = L[LM_TC + el * 6 + o + 2];
  sc[(long)(25 + o) * Bl + e] = L[LM_TC + el * 6 + o + 4];
}

// ================= u kernel (octet E=2, 1024 thr, 256 el) =================
__global__ __launch_bounds__(1024, 1) void urole_kernel(
    const float* __restrict__ in, const float* __restrict__ ws, const float* __restrict__ u_W0,
    const float* __restrict__ u_b0, const float* __restrict__ u_Wh, const float* __restrict__ u_bh,
    const float* __restrict__ u_Wo, float* __restrict__ sc, int B) {
  __shared__ __align__(16) float L[LU_TOT];
  const int t = threadIdx.x;
  cpy4n(L + L_W0P, ws + W0P_U, 64, t, 1024);
  stage36n(L + L_WHT, ws + UWHT, 128, t, 1024);
  stage36n(L + LU_WHO, u_Wh, 128, t, 1024);
  cpy4n(L + LU_WO, u_Wo, 8, t, 1024);
  stage36n(L + LU_W0O, u_W0, 6, t, 1024);
  cpysn(L + LU_B0, u_b0, 32, t, 1024);
  cpysn(L + LU_BH, u_bh, 128, t, 1024);
  __syncthreads();

  const int oid = t >> 3, o = t & 7;
  const int e0 = blockIdx.x * 256 + oid;
  if (e0 >= B) return;
  const int e1 = e0 + 128;
  const bool has1 = e1 < B;
  const int el0 = oid, el1 = oid + 128;
  const float* ip0 = in + (long)e0 * 18;
  const float* ip1 = in + (long)(has1 ? e1 : e0) * 18;
  const long Bl = B;

  float X0[6], X1[6];
#pragma unroll
  for (int i = 0; i < 6; i++) {
    X0[i] = ip0[i];
    X1[i] = ip1[i];
  }
  float* S0 = L + LU_S + el0 * 36;
  float* S1 = L + LU_S + el1 * 36;
  float* HB0 = L + LU_HB + el0 * 36;
  float* HB1 = L + LU_HB + el1 * 36;
  float* HD0 = L + LU_HD + el0 * 36;
  float* HD1 = L + LU_HD + el1 * 36;
#pragma unroll
  for (int m4 = 0; m4 < 4; m4++) {
    int j = o + 8 * m4;
    float4 wa = *(const float4*)&L[L_W0P + j * 8];
    float4 wb = *(const float4*)&L[L_W0P + j * 8 + 4];
    float b = L[LU_B0 + j];
    S0[j] = sp1(b + X0[0] * wa.x + X0[1] * wa.y + X0[2] * wa.z + X0[3] * wa.w + X0[4] * wb.x +
                X0[5] * wb.y);
    S1[j] = sp1(b + X1[0] * wa.x + X1[1] * wa.y + X1[2] * wa.z + X1[3] * wa.w + X1[4] * wb.x +
                X1[5] * wb.y);
  }
  coopFwd2O(L + L_WHT + 0 * 1152, L + LU_BH + 0, S0, S1, HB0, HB1, o);
  coopFwd2O(L + L_WHT + 1 * 1152, L + LU_BH + 32, HB0, HB1, S0, S1, o);
  coopFwd2O(L + L_WHT + 2 * 1152, L + LU_BH + 64, S0, S1, HD0, HD1, o);
  coopFwd2O(L + L_WHT + 3 * 1152, L + LU_BH + 96, HD0, HD1, S0, S1, o);
#pragma unroll
  for (int m4 = 0; m4 < 4; m4++) {
    int j = o + 8 * m4;
    float wo = L[LU_WO + j];
    S0[j] = wo * sig_h(S0[j]);
    S1[j] = wo * sig_h(S1[j]);
  }
  coopBwd2O(L + LU_WHO + 3 * 1152, S0, S1, S0, S1, o);
#pragma unroll
  for (int m4 = 0; m4 < 4; m4++) {
    int j = o + 8 * m4;
    S0[j] = S0[j] * sig_h(HD0[j]);
    S1[j] = S1[j] * sig_h(HD1[j]);
  }
  coopBwd2O(L + LU_WHO + 2 * 1152, S0, S1, HD0, HD1, o);
  coopFwd2O(L + L_WHT + 1 * 1152, L + LU_BH + 32, HB0, HB1, S0, S1, o);  // recompute hc
#pragma unroll
  for (int m4 = 0; m4 < 4; m4++) {
    int j = o + 8 * m4;
    HD0[j] = HD0[j] * sig_h(S0[j]);
    HD1[j] = HD1[j] * sig_h(S1[j]);
  }
  coopBwd2O(L + LU_WHO + 1 * 1152, HD0, HD1, S0, S1, o);
#pragma unroll
  for (int m4 = 0; m4 < 4; m4++) {
    int j = o + 8 * m4;
    HB0[j] = S0[j] * sig_h(HB0[j]);
    HB1[j] = S1[j] * sig_h(HB1[j]);
  }
  coopBwd2O(L + LU_WHO + 0 * 1152, HB0, HB1, HD0, HD1, o);
#pragma unroll
  for (int m4 = 0; m4 < 4; m4++) {
    int j = o + 8 * m4;
    float4 wa = *(const float4*)&L[L_W0P + j * 8];
    float4 wb = *(const float4*)&L[L_W0P + j * 8 + 4];
    float b = L[LU_B0 + j];
    float a0 = sp1(b + X0[0] * wa.x + X0[1] * wa.y + X0[2] * wa.z + X0[3] * wa.w + X0[4] * wb.x +
                   X0[5] * wb.y);
    float a1 = sp1(b + X1[0] * wa.x + X1[1] * wa.y + X1[2] * wa.z + X1[3] * wa.w + X1[4] * wb.x +
                   X1[5] * wb.y);
    S0[j] = HD0[j] * sig_h(a0);
    S1[j] = HD1[j] * sig_h(a1);
  }
  if (o < 6) {
    float a0[32], a1[32];
    load32(S0, a0);
    load32(S1, a1);
    const float* r = L + LU_W0O + o * 36;
    float tp0 = 0.f, tp1 = 0.f;
#pragma unroll
    for (int c = 0; c < 8; c++) {
      float4 w = *(const float4*)&r[4 * c];
      tp0 += a0[4 * c + 0] * w.x + a0[4 * c + 1] * w.y + a0[4 * c + 2] * w.z + a0[4 * c + 3] * w.w;
      tp1 += a1[4 * c + 0] * w.x + a1[4 * c + 1] * w.y + a1[4 * c + 2] * w.z + a1[4 * c + 3] * w.w;
    }
    sc[(long)(27 + o) * Bl + e0] = tp0;
    if (has1) sc[(long)(27 + o) * Bl + e1] = tp1;
  }
}

// ================= d kernel (quad E=2, 256 thr, 128 el) =================
__global__ __launch_bounds__(256, 1) void drole_kernel(const float* __restrict__ in,
                                                       const float* __restrict__ ws,
                                                       const float* __restrict__ d_b0,
                                                       const float* __restrict__ d_bh,
                                                       const float* __restrict__ d_bo,
                                                       float* __restrict__ sc, int B) {
  __shared__ __align__(16) float L[LD_TOT];
  const int t = threadIdx.x;
  cpy4n(L + L_W0P, ws + W0P_D, 64, t, 256);
  stage36n(L + L_WHT, ws + DWHT, 128, t, 256);
  stage36n(L + LD_WOT, ws + DWOT, 36, t, 256);
  cpysn(L + LD_B0, d_b0, 32, t, 256);
  cpysn(L + LD_BH, d_bh, 128, t, 256);
  cpysn(L + LD_BO, d_bo, 36, t, 256);
  __syncthreads();

  const int qid = t >> 2, q = t & 3;
  const int e0 = blockIdx.x * 128 + qid;
  if (e0 >= B) return;
  const int e1 = e0 + 64;
  const bool has1 = e1 < B;
  const int el0 = qid, el1 = qid + 64;
  const float* ip0 = in + (long)e0 * 18;
  const float* ip1 = in + (long)(has1 ? e1 : e0) * 18;
  const long Bl = B;

  float X0[6], X1[6];
#pragma unroll
  for (int i = 0; i < 6; i++) {
    X0[i] = ip0[i];
    X1[i] = ip1[i];
  }
  float* S0 = L + LD_S + el0 * 36;
  float* S1 = L + LD_S + el1 * 36;
#pragma unroll 2
  for (int m8 = 0; m8 < 8; m8++) {
    int j = q + 4 * m8;
    float4 wa = *(const float4*)&L[L_W0P + j * 8];
    float4 wb = *(const float4*)&L[L_W0P + j * 8 + 4];
    float b = L[LD_B0 + j];
    S0[j] = sp1(b + X0[0] * wa.x + X0[1] * wa.y + X0[2] * wa.z + X0[3] * wa.w + X0[4] * wb.x +
                X0[5] * wb.y);
    S1[j] = sp1(b + X1[0] * wa.x + X1[1] * wa.y + X1[2] * wa.z + X1[3] * wa.w + X1[4] * wb.x +
                X1[5] * wb.y);
  }
#pragma unroll 1
  for (int l = 0; l < 4; l++)
    coopFwd2(L + L_WHT + l * 1152, L + LD_BH + l * 32, S0, S1, S0, S1, q);
  float a0[32], a1[32];
  load32(S0, a0);
  load32(S1, a1);
#pragma unroll 1
  for (int mm = 0; mm < 2; mm++) {
    int i = q + 4 * mm;
    if (i < 6) {
      float td0 = 0.f, td1 = 0.f;
#pragma unroll 1
      for (int c = 0; c < 6; c++) {
        const float* r = L + LD_WOT + (i * 6 + c) * 36;
        float b = L[LD_BO + i * 6 + c];
        float v0 = b, v1 = b;
#pragma unroll
        for (int cc = 0; cc < 8; cc++) {
          float4 w = *(const float4*)&r[4 * cc];
          v0 += a0[4 * cc + 0] * w.x + a0[4 * cc + 1] * w.y + a0[4 * cc + 2] * w.z +
                a0[4 * cc + 3] * w.w;
          v1 += a1[4 * cc + 0] * w.x + a1[4 * cc + 1] * w.y + a1[4 * cc + 2] * w.z +
                a1[4 * cc + 3] * w.w;
        }
        td0 += v0 * ip0[6 + c];
        td1 += v1 * ip1[6 + c];
      }
      sc[(long)(33 + i) * Bl + e0] = td0;
      if (has1) sc[(long)(33 + i) * Bl + e1] = td1;
    }
  }
}

// ---------------- combine + solve (unchanged) ----------------
__global__ __launch_bounds__(256) void combine_kernel(const float* __restrict__ in,
                                                      const float* __restrict__ A,
                                                      const float* __restrict__ sc,
                                                      float* __restrict__ out, int B) {
  int b = blockIdx.x * 256 + threadIdx.x;
  if (b >= B) return;
  const long Bl = B;
  const float* ip = in + (long)b * 18;
  float te[6];
  {
    float tv[6];
#pragma unroll
    for (int i = 0; i < 6; i++) tv[i] = ip[12 + i];
#pragma unroll
    for (int i = 0; i < 6; i++) {
      float s = 0.f;
#pragma unroll
      for (int j = 0; j < 6; j++) s += tv[j] * A[j * 6 + i];
      te[i] = s;
    }
  }
  float Ms[6][6], r[6], y[6];
  {
    int idx = 0;
#pragma unroll
    for (int i = 0; i < 6; i++)
#pragma unroll
      for (int j = i; j < 6; j++) {
        float v = sc[idx * Bl + b];
        Ms[i][j] = v;
        Ms[j][i] = v;
        idx++;
      }
  }
#pragma unroll
  for (int i = 0; i < 6; i++)
    r[i] = te[i] - sc[(21 + i) * Bl + b] - sc[(27 + i) * Bl + b] - sc[(33 + i) * Bl + b];

#pragma unroll
  for (int k = 0; k < 6; k++) {
#pragma unroll
    for (int rr = k + 1; rr < 6; rr++) {
      bool c = fabsf(Ms[rr][k]) > fabsf(Ms[k][k]);
#pragma unroll
      for (int j = 0; j < 6; j++) {
        float a = Ms[k][j], bb = Ms[rr][j];
        Ms[k][j] = c ? bb : a;
        Ms[rr][j] = c ? a : bb;
      }
      float a = r[k], bb = r[rr];
      r[k] = c ? bb : a;
      r[rr] = c ? a : bb;
    }
    float piv = Ms[k][k];
#pragma unroll
    for (int rr = k + 1; rr < 6; rr++) {
      float f = Ms[rr][k] / piv;
#pragma unroll
      for (int j = k; j < 6; j++) Ms[rr][j] -= f * Ms[k][j];
      r[rr] -= f * r[k];
    }
  }
#pragma unroll
  for (int ki = 5; ki >= 0; ki--) {
    float v = r[ki];
#pragma unroll
    for (int j = ki + 1; j < 6; j++) v -= Ms[ki][j] * y[j];
    y[ki] = v / Ms[ki][ki];
  }
  float* op = out + (long)b * 6;
#pragma unroll
  for (int i = 0; i < 6; i++) op[i] = y[i];
}

// ---------------- fallback monolithic kernel ----------------
__device__ __forceinline__ void fwd_layer(const float* __restrict__ Wb,
                                          const float* __restrict__ bh,
                                          const float* __restrict__ hin, float* __restrict__ hout) {
#pragma unroll
  for (int j = 0; j < 32; j++) {
    const float* r = Wb + j * 32;
    float z = bh[j];
#pragma unroll
    for (int k = 0; k < 32; k++) z += hin[k] * r[k];
    hout[j] = sp1(z);
  }
}
__device__ __forceinline__ void m_layer(const float* __restrict__ Wb, const float* __restrict__ bh,
                                        float* __restrict__ h, const float* __restrict__ tin,
                                        float* __restrict__ tout) {
#pragma unroll
  for (int j = 0; j < 32; j++) {
    const float* r = Wb + j * 32;
    float z = bh[j];
#pragma unroll
    for (int k = 0; k < 32; k++) z += h[k] * r[k];
    tout[j] = z;
  }
#pragma unroll
  for (int j = 0; j < 32; j++) {
    const float* r = Wb + j * 32;
    float z = 0.f;
#pragma unroll
    for (int k = 0; k < 32; k++) z += tin[k] * r[k];
    float hs, sg;
    sp_sig(tout[j], hs, sg);
    h[j] = hs;
    tout[j] = z * sg;
  }
}
__device__ __forceinline__ void bwd_mv(const float* __restrict__ Worig,
                                       const float* __restrict__ gin, float* __restrict__ gout) {
#pragma unroll
  for (int k = 0; k < 32; k++) {
    const float* r = Worig + k * 32;
    float s = 0.f;
#pragma unroll
    for (int j = 0; j < 32; j++) s += r[j] * gin[j];
    gout[k] = s;
  }
}

__global__ __launch_bounds__(64, 1) void lnn_kernel(
    const float* __restrict__ in, const float* __restrict__ A, const float* __restrict__ ws,
    const float* __restrict__ m_b0, const float* __restrict__ m_bh, const float* __restrict__ m_bo,
    const float* __restrict__ u_W0, const float* __restrict__ u_b0, const float* __restrict__ u_Wh,
    const float* __restrict__ u_bh, const float* __restrict__ u_Wo,
    const float* __restrict__ d_b0, const float* __restrict__ d_bh, const float* __restrict__ d_bo,
    float* __restrict__ out, int B) {
  int b = blockIdx.x * 64 + threadIdx.x;
  if (b >= B) return;
  const float* ip = in + (long)b * 18;
  float x[6], xd[6], te[6];
#pragma unroll
  for (int i = 0; i < 6; i++) {
    x[i] = ip[i];
    xd[i] = ip[6 + i];
  }
  {
    float tv[6];
#pragma unroll
    for (int i = 0; i < 6; i++) tv[i] = ip[12 + i];
#pragma unroll
    for (int i = 0; i < 6; i++) {
      float s = 0.f;
#pragma unroll
      for (int j = 0; j < 6; j++) s += tv[j] * A[j * 6 + i];
      te[i] = s;
    }
  }
  float td[6] = {0, 0, 0, 0, 0, 0};
  {
    float h[32], zn[32];
    const float* w0 = ws + DW0T;
#pragma unroll
    for (int j = 0; j < 32; j++) {
      float z = d_b0[j];
#pragma unroll
      for (int k = 0; k < 6; k++) z += x[k] * w0[j * 6 + k];
      h[j] = sp1(z);
    }
    fwd_layer(ws + DWHT + 0 * 1024, d_bh + 0, h, zn);
    fwd_layer(ws + DWHT + 1 * 1024, d_bh + 32, zn, h);
    fwd_layer(ws + DWHT + 2 * 1024, d_bh + 64, h, zn);
    fwd_layer(ws + DWHT + 3 * 1024, d_bh + 96, zn, h);
    const float* wo = ws + DWOT;
#pragma unroll
    for (int o = 0; o < 36; o++) {
      float v = d_bo[o];
#pragma unroll
      for (int k = 0; k < 32; k++) v += h[k] * wo[o * 32 + k];
      td[o / 6] += v * xd[o % 6];
    }
  }
  float tp[6] = {0, 0, 0, 0, 0, 0};
  {
    float hb[32], hd[32], s[32], r2[32];
    const float* w0 = ws + UW0T;
#pragma unroll
    for (int j = 0; j < 32; j++) {
      float z = u_b0[j];
#pragma unroll
      for (int k = 0; k < 6; k++) z += x[k] * w0[j * 6 + k];
      s[j] = sp1(z);
    }
    fwd_layer(ws + UWHT + 0 * 1024, u_bh + 0, s, hb);
    fwd_layer(ws + UWHT + 1 * 1024, u_bh + 32, hb, s);
    fwd_layer(ws + UWHT + 2 * 1024, u_bh + 64, s, hd);
    fwd_layer(ws + UWHT + 3 * 1024, u_bh + 96, hd, s);
#pragma unroll
    for (int j = 0; j < 32; j++) s[j] = u_Wo[j] * sig_h(s[j]);
    bwd_mv(u_Wh + 3 * 1024, s, r2);
#pragma unroll
    for (int j = 0; j < 32; j++) s[j] = r2[j] * sig_h(hd[j]);
    bwd_mv(u_Wh + 2 * 1024, s, hd);
    fwd_layer(ws + UWHT + 1 * 1024, u_bh + 32, hb, s);
#pragma unroll
    for (int j = 0; j < 32; j++) r2[j] = hd[j] * sig_h(s[j]);
    bwd_mv(u_Wh + 1 * 1024, r2, s);
#pragma unroll
    for (int j = 0; j < 32; j++) r2[j] = s[j] * sig_h(hb[j]);
    bwd_mv(u_Wh + 0 * 1024, r2, hb);
#pragma unroll
    for (int j = 0; j < 32; j++) {
      float z = u_b0[j];
#pragma unroll
      for (int k = 0; k < 6; k++) z += x[k] * w0[j * 6 + k];
      s[j] = sp1(z);
    }
#pragma unroll
    for (int j = 0; j < 32; j++) s[j] = hb[j] * sig_h(s[j]);
#pragma unroll
    for (int i = 0; i < 6; i++) {
      float t = 0.f;
#pragma unroll
      for (int j = 0; j < 32; j++) t += u_W0[i * 32 + j] * s[j];
      tp[i] = t;
    }
  }
  float Ms[6][6], tc[6];
  {
    float h[32], t[32], zn[32];
    const float* w0 = ws + MW0T;
#pragma unroll
    for (int j = 0; j < 32; j++) {
      float zh = m_b0[j], zt = 0.f;
#pragma unroll
      for (int k = 0; k < 6; k++) {
        zh += x[k] * w0[j * 6 + k];
        zt += xd[k] * w0[j * 6 + k];
      }
      float hs, sg;
      sp_sig(zh, hs, sg);
      h[j] = hs;
      t[j] = zt * sg;
    }
    m_layer(ws + MWHT + 0 * 1024, m_bh + 0, h, t, zn);
    m_layer(ws + MWHT + 1 * 1024, m_bh + 32, h, zn, t);
    m_layer(ws + MWHT + 2 * 1024, m_bh + 64, h, t, zn);
    m_layer(ws + MWHT + 3 * 1024, m_bh + 96, h, zn, t);
    const float* wo = ws + MWOT;
    float Msv[21];
    int idx = 0;
#pragma unroll
    for (int i = 0; i < 6; i++) tc[i] = 0.f;
#pragma unroll
    for (int i = 0; i < 6; i++)
#pragma unroll
      for (int j = i; j < 6; j++) {
        const float* r = wo + (i * 6 + j) * 32;
        float v = m_bo[i * 6 + j], w = 0.f;
#pragma unroll
        for (int k = 0; k < 32; k++) {
          v += h[k] * r[k];
          w += t[k] * r[k];
        }
        if (i != j) {
          const float* rr = wo + (j * 6 + i) * 32;
          float v2 = m_bo[j * 6 + i], w2 = 0.f;
#pragma unroll
          for (int k = 0; k < 32; k++) {
            v2 += h[k] * rr[k];
            w2 += t[k] * rr[k];
          }
          v = 0.5f * (v + v2);
          w = 0.5f * (w + w2);
        }
        Msv[idx] = v;
        tc[i] += w * xd[j];
        if (j != i) tc[j] += w * xd[i];
        idx++;
      }
    idx = 0;
#pragma unroll
    for (int i = 0; i < 6; i++)
#pragma unroll
      for (int j = i; j < 6; j++) {
        Ms[i][j] = Msv[idx];
        Ms[j][i] = Msv[idx];
        idx++;
      }
  }
  float r[6], y[6];
#pragma unroll
  for (int i = 0; i < 6; i++) r[i] = te[i] - tc[i] - tp[i] - td[i];
#pragma unroll
  for (int k = 0; k < 6; k++) {
#pragma unroll
    for (int rr = k + 1; rr < 6; rr++) {
      bool c = fabsf(Ms[rr][k]) > fabsf(Ms[k][k]);
#pragma unroll
      for (int j = 0; j < 6; j++) {
        float a = Ms[k][j], bb = Ms[rr][j];
        Ms[k][j] = c ? bb : a;
        Ms[rr][j] = c ? a : bb;
      }
      float a = r[k], bb = r[rr];
      r[k] = c ? bb : a;
      r[rr] = c ? a : bb;
    }
    float piv = Ms[k][k];
#pragma unroll
    for (int rr = k + 1; rr < 6; rr++) {
      float f = Ms[rr][k] / piv;
#pragma unroll
      for (int j = k; j < 6; j++) Ms[rr][j] -= f * Ms[k][j];
      r[rr] -= f * r[k];
    }
  }
#pragma unroll
  for (int ki = 5; ki >= 0; ki--) {
    float v = r[ki];
#pragma unroll
    for (int j = ki + 1; j < 6; j++) v -= Ms[ki][j] * y[j];
    y[ki] = v / Ms[ki][ki];
  }
  float* op = out + (long)b * 6;
#pragma unroll
  for (int i = 0; i < 6; i++) op[i] = y[i];
}

extern "C" void kernel_launch(void* const* d_in, const int* in_sizes, int n_in, void* d_out,
                              int out_size, void* d_ws, size_t ws_size, hipStream_t stream) {
  const float* inputs = (const float*)d_in[0];
  const float* A = (const float*)d_in[1];
  const float* m_W0 = (const float*)d_in[2];
  const float* m_b0 = (const float*)d_in[3];
  const float* m_Wh = (const float*)d_in[4];
  const float* m_bh = (const float*)d_in[5];
  const float* m_Wo = (const float*)d_in[6];
  const float* m_bo = (const float*)d_in[7];
  const float* u_W0 = (const float*)d_in[8];
  const float* u_b0 = (const float*)d_in[9];
  const float* u_Wh = (const float*)d_in[10];
  const float* u_bh = (const float*)d_in[11];
  const float* u_Wo = (const float*)d_in[12];
  const float* d_W0 = (const float*)d_in[14];
  const float* d_b0 = (const float*)d_in[15];
  const float* d_Wh = (const float*)d_in[16];
  const float* d_bh = (const float*)d_in[17];
  const float* d_Wo = (const float*)d_in[18];
  const float* d_bo = (const float*)d_in[19];

  float* ws = (float*)d_ws;
  float* out = (float*)d_out;
  int B = in_sizes[0] / 18;

  prep_kernel<<<16, 256, 0, stream>>>(m_W0, m_Wh, m_Wo, m_bo, u_W0, u_Wh, u_Wo, d_W0, d_Wh, d_Wo,
                                      ws);

  size_t need = (size_t)(SC_BASE + (size_t)B * 39) * 4;
  if (ws_size >= need) {
    float* sc = ws + SC_BASE;
    int nb_m = (B + 255) / 256;  // pair decomp: 256 el/block, 1 block/CU uniform
    int nb_d = (B + 127) / 128;
    int nb_u = (B + 255) / 256;
    mrole_kernel<<<nb_m, 512, 0, stream>>>(inputs, ws, m_b0, m_bh, sc, B);
    urole_kernel<<<nb_u, 1024, 0, stream>>>(inputs, ws, u_W0, u_b0, u_Wh, u_bh, u_Wo, sc, B);
    drole_kernel<<<nb_d, 256, 0, stream>>>(inputs, ws, d_b0, d_bh, d_bo, sc, B);
    combine_kernel<<<(B + 255) / 256, 256, 0, stream>>>(inputs, A, sc, out, B);
  } else {
    lnn_kernel<<<(B + 63) / 64, 64, 0, stream>>>(inputs, A, ws, m_b0, m_bh, m_bo, u_W0, u_b0, u_Wh,
                                                 u_bh, u_Wo, d_b0, d_bh, d_bo, out, B);
  }
}